// Round 5
// baseline (482.082 us; speedup 1.0000x reference)
//
#include <hip/hip_runtime.h>
#include <hip/hip_bf16.h>

#define DTC 0.1f
#define ACTION_RANGE 50.0f
#define MAX_VEL 20.0f
#define PI_F 3.14159265358979323846f
#define TWO_PI_F 6.28318530717958647692f
#define INV_TWO_PI_F 0.15915494309189533577f

__device__ __forceinline__ float bf2f(__hip_bfloat16 x){ return __bfloat162float(x); }
__device__ __forceinline__ float frcp(float x){ return __builtin_amdgcn_rcpf(x); }

// dtype-dispatched load/store (verified: inputs are bf16, but keep robust)
__device__ __forceinline__ float ldv(const void* p, int i, bool isb){
  return isb ? __bfloat162float(((const __hip_bfloat16*)p)[i]) : ((const float*)p)[i];
}
__device__ __forceinline__ void stv(void* p, int i, float v, bool isb){
  if (isb) ((__hip_bfloat16*)p)[i] = __float2bfloat16(v);
  else     ((float*)p)[i] = v;
}

// Branchless exp(se3): native __sinf/__cosf + Taylor blend.
// Validated rounds 1/2/4: absmax stays at bf16 floor (0.0078125).
// At s==0: small path -> R=I, P=0 exactly (used by the uniform lane-7 path).
__device__ __forceinline__ void exp_se3_Rp(const float* Aj, float s, float* R, float* P){
  float wx=Aj[0]*s, wy=Aj[1]*s, wz=Aj[2]*s;
  float vx=Aj[3]*s, vy=Aj[4]*s, vz=Aj[5]*s;
  float th2 = wx*wx+wy*wy+wz*wz;
  float th = sqrtf(th2);
  float th4 = th2*th2;
  float aS = 1.f - th2*(1.f/6.f)  + th4*(1.f/120.f);
  float bS = 0.5f - th2*(1.f/24.f) + th4*(1.f/720.f);
  float cS = (1.f/6.f) - th2*(1.f/120.f) + th4*(1.f/5040.f);
  float sn = __sinf(th), cs = __cosf(th);
  float inv = frcp(th), inv2 = inv*inv;
  float aL = sn*inv;             // NaN at th=0, selected away
  float bL = (1.f-cs)*inv2;
  float cL = (th-sn)*inv2*inv;
  bool sm = th < 0.25f;
  float a = sm?aS:aL, b = sm?bS:bL, c = sm?cS:cL;
  R[0]=1.f+b*(wx*wx-th2); R[1]=b*wx*wy-a*wz;      R[2]=b*wx*wz+a*wy;
  R[3]=b*wx*wy+a*wz;      R[4]=1.f+b*(wy*wy-th2); R[5]=b*wy*wz-a*wx;
  R[6]=b*wx*wz-a*wy;      R[7]=b*wy*wz+a*wx;      R[8]=1.f+b*(wz*wz-th2);
  float V0=1.f+c*(wx*wx-th2), V1=c*wx*wy-b*wz,      V2=c*wx*wz+b*wy;
  float V3=c*wx*wy+b*wz,      V4=1.f+c*(wy*wy-th2), V5=c*wy*wz-b*wx;
  float V6=c*wx*wz-b*wy,      V7=c*wy*wz+b*wx,      V8=1.f+c*(wz*wz-th2);
  P[0]=V0*vx+V1*vy+V2*vz;
  P[1]=V3*vx+V4*vy+V5*vz;
  P[2]=V6*vx+V7*vy+V8*vz;
}

__device__ __forceinline__ void mul33(const float* X, const float* Y, float* Z){
  #pragma unroll
  for (int r=0;r<3;r++){
    float x0=X[r*3+0], x1=X[r*3+1], x2=X[r*3+2];
    Z[r*3+0]=x0*Y[0]+x1*Y[3]+x2*Y[6];
    Z[r*3+1]=x0*Y[1]+x1*Y[4]+x2*Y[7];
    Z[r*3+2]=x0*Y[2]+x1*Y[5]+x2*Y[8];
  }
}

// V' = Ad(T) V (alias-safe)
__device__ __forceinline__ void ad_apply(const float* R, const float* p, const float* Vin, float* Vout){
  float i0=Vin[0],i1=Vin[1],i2=Vin[2],i3=Vin[3],i4=Vin[4],i5=Vin[5];
  float w0 = R[0]*i0+R[1]*i1+R[2]*i2;
  float w1 = R[3]*i0+R[4]*i1+R[5]*i2;
  float w2 = R[6]*i0+R[7]*i1+R[8]*i2;
  float r0 = R[0]*i3+R[1]*i4+R[2]*i5;
  float r1 = R[3]*i3+R[4]*i4+R[5]*i5;
  float r2 = R[6]*i3+R[7]*i4+R[8]*i5;
  float p0=p[0],p1=p[1],p2=p[2];
  Vout[0]=w0; Vout[1]=w1; Vout[2]=w2;
  Vout[3]=p1*w2-p2*w1+r0;
  Vout[4]=p2*w0-p0*w2+r1;
  Vout[5]=p0*w1-p1*w0+r2;
}

// F' = Ad(T)^T F (alias-safe)
__device__ __forceinline__ void adT_apply(const float* R, const float* p, const float* Fin, float* Fout){
  float m0=Fin[0],m1=Fin[1],m2=Fin[2],f0=Fin[3],f1=Fin[4],f2=Fin[5];
  float p0=p[0],p1=p[1],p2=p[2];
  float cx = m0 - (p1*f2 - p2*f1);
  float cy = m1 - (p2*f0 - p0*f2);
  float cz = m2 - (p0*f1 - p1*f0);
  float o0 = R[0]*cx + R[3]*cy + R[6]*cz;
  float o1 = R[1]*cx + R[4]*cy + R[7]*cz;
  float o2 = R[2]*cx + R[5]*cy + R[8]*cz;
  float o3 = R[0]*f0 + R[3]*f1 + R[6]*f2;
  float o4 = R[1]*f0 + R[4]*f1 + R[7]*f2;
  float o5 = R[2]*f0 + R[5]*f1 + R[8]*f2;
  Fout[0]=o0;Fout[1]=o1;Fout[2]=o2;Fout[3]=o3;Fout[4]=o4;Fout[5]=o5;
}

// Both G-matvecs from symmetric-packed Gu (21 floats, LDS broadcast).
// Same per-row FMA order (c=0..5) as the dense version -> bit-identical.
__device__ __forceinline__ void gmatvec2_sym(const float* Gu, const float* v, const float* d,
                                             float* gv, float* gvd){
  float g0=Gu[0],g1=Gu[1],g2=Gu[2],g3=Gu[3],g4=Gu[4],g5=Gu[5];
  float g6=Gu[6],g7=Gu[7],g8=Gu[8],g9=Gu[9],g10=Gu[10];
  float g11=Gu[11],g12=Gu[12],g13=Gu[13],g14=Gu[14];
  float g15=Gu[15],g16=Gu[16],g17=Gu[17],g18=Gu[18],g19=Gu[19],g20=Gu[20];
  gv[0]=g0*v[0]+g1 *v[1]+g2 *v[2]+g3 *v[3]+g4 *v[4]+g5 *v[5];
  gv[1]=g1*v[0]+g6 *v[1]+g7 *v[2]+g8 *v[3]+g9 *v[4]+g10*v[5];
  gv[2]=g2*v[0]+g7 *v[1]+g11*v[2]+g12*v[3]+g13*v[4]+g14*v[5];
  gv[3]=g3*v[0]+g8 *v[1]+g12*v[2]+g15*v[3]+g16*v[4]+g17*v[5];
  gv[4]=g4*v[0]+g9 *v[1]+g13*v[2]+g16*v[3]+g18*v[4]+g19*v[5];
  gv[5]=g5*v[0]+g10*v[1]+g14*v[2]+g17*v[3]+g19*v[4]+g20*v[5];
  gvd[0]=g0*d[0]+g1 *d[1]+g2 *d[2]+g3 *d[3]+g4 *d[4]+g5 *d[5];
  gvd[1]=g1*d[0]+g6 *d[1]+g7 *d[2]+g8 *d[3]+g9 *d[4]+g10*d[5];
  gvd[2]=g2*d[0]+g7 *d[1]+g11*d[2]+g12*d[3]+g13*d[4]+g14*d[5];
  gvd[3]=g3*d[0]+g8 *d[1]+g12*d[2]+g15*d[3]+g16*d[4]+g17*d[5];
  gvd[4]=g4*d[0]+g9 *d[1]+g13*d[2]+g16*d[3]+g18*d[4]+g19*d[5];
  gvd[5]=g5*d[0]+g10*d[1]+g14*d[2]+g17*d[3]+g19*d[4]+g20*d[5];
}

__global__ __launch_bounds__(64) void arm_rk4_kernel(
    const void* __restrict__ g_state,
    const void* __restrict__ g_torque,
    const void* __restrict__ g_M,
    const void* __restrict__ g_A,
    const void* __restrict__ g_L,
    const void* __restrict__ g_grav,
    const void* __restrict__ g_ftip,
    void* __restrict__ g_out,
    int B)
{
  __shared__ float sA[42];       // A[7][6]
  __shared__ float sGu[147];     // G = L L^T, symmetric-packed 21/joint
  __shared__ float sMinvR[72];   // inv(M_i): R^T, i=0..7
  __shared__ float sMinvp[24];   //            -R^T p
  __shared__ float sMR[72];      // M_i rotation (FK)
  __shared__ float sMp[24];      // M_i translation
  __shared__ float sgrav[3];
  __shared__ float sftip[6];

  const bool isb = fabsf(bf2f(((const __hip_bfloat16*)g_grav)[1]) + 9.8f) < 0.5f;

  const int t = threadIdx.x;
  for (int x=t; x<42; x+=64) sA[x] = ldv(g_A, x, isb);
  for (int x=t; x<147; x+=64){
    int i = x/21; int u = x - i*21;
    int rr = 0, u2 = u;
    while (u2 >= 6-rr){ u2 -= 6-rr; rr++; }   // init-only scalar loop
    int cc = rr + u2;
    float s = 0.f;
    #pragma unroll
    for (int k=0;k<6;k++) s += ldv(g_L, i*36+rr*6+k, isb) * ldv(g_L, i*36+cc*6+k, isb);
    sGu[x] = s;
  }
  if (t < 8){
    float R[9], p[3];
    #pragma unroll
    for (int rr=0;rr<3;rr++){
      #pragma unroll
      for (int cc=0;cc<3;cc++) R[rr*3+cc] = ldv(g_M, t*16 + rr*4 + cc, isb);
      p[rr] = ldv(g_M, t*16 + rr*4 + 3, isb);
    }
    #pragma unroll
    for (int rr=0;rr<3;rr++){
      #pragma unroll
      for (int cc=0;cc<3;cc++){ sMR[t*9+rr*3+cc] = R[rr*3+cc]; sMinvR[t*9+rr*3+cc] = R[cc*3+rr]; }
      sMp[t*3+rr] = p[rr];
      sMinvp[t*3+rr] = -(R[0*3+rr]*p[0] + R[1*3+rr]*p[1] + R[2*3+rr]*p[2]);
    }
  }
  if (t == 0){ for (int k=0;k<3;k++) sgrav[k] = ldv(g_grav, k, isb); }
  if (t == 1){ for (int k=0;k<6;k++) sftip[k] = ldv(g_ftip, k, isb); }
  __syncthreads();               // ONLY barrier in the kernel

  const int e = t >> 3;          // element within block (0..7)
  const int r = t & 7;           // role: 0..6 = mass row/col r ; 7 = bias torque h
  int b = blockIdx.x * 8 + e;
  if (b >= B) b = B - 1;         // safe clamp (B divisible by 8 in practice)
  const bool is7 = (r == 7);
  const int ar = is7 ? 6 : r;    // A row for uniform transform (lane7: q=0 -> unused)

  // replicated per-element state
  float q0[7], dq0[7], qf[7];
  #pragma unroll
  for (int i=0;i<7;i++){
    q0[i]  = ldv(g_state, b*14+i, isb);
    dq0[i] = ldv(g_state, b*14+7+i, isb);
    qf[i]  = ldv(g_torque, b*7+i, isb) * ACTION_RANGE;
  }
  float kq[7], kdd[7], accq[7], accdq[7];
  #pragma unroll
  for (int i=0;i<7;i++){ kq[i]=0.f; kdd[i]=0.f; accq[i]=0.f; accdq[i]=0.f; }

  // role-dependent tip wrench (constant across stages): role7 gets AdT_end^T ftip
  float Fend[6];
  {
    float tf[6]; adT_apply(&sMinvR[63], &sMinvp[21], sftip, tf);
    #pragma unroll
    for (int k=0;k<6;k++) Fend[k] = is7 ? tf[k] : 0.f;
  }

  #pragma unroll 1
  for (int st=0; st<4; ++st){
    const float cin = (st==0) ? 0.f : ((st==3) ? DTC : 0.5f*DTC);
    const float wgt = (st==0||st==3) ? (DTC/6.f) : (DTC/3.f);
    float qs[7], dqs[7];
    #pragma unroll
    for (int i=0;i<7;i++){ qs[i]=q0[i]+cin*kq[i]; dqs[i]=dq0[i]+cin*kdd[i]; }

    // own joint angle (scalar extraction; 0 for lane 7)
    float qsr = 0.f;
    #pragma unroll
    for (int c=0;c<7;c++) qsr = (r==c) ? qs[c] : qsr;

    // ---- transforms: UNIFORM compute, kept in registers (no LDS, no barrier)
    // lane r<7: T_r = exp(-A_r q_r) inv(M_r); lane 7: q=0 -> inv(M_7), unused.
    float Tmy[12];
    {
      float Re[9], Pe[3], Rt[9];
      exp_se3_Rp(&sA[ar*6], -qsr, Re, Pe);
      mul33(Re, &sMinvR[r*9], Rt);
      #pragma unroll
      for (int k=0;k<9;k++) Tmy[k] = Rt[k];
      #pragma unroll
      for (int rr=0;rr<3;rr++)
        Tmy[9+rr] = Re[rr*3+0]*sMinvp[r*3+0] + Re[rr*3+1]*sMinvp[r*3+1]
                  + Re[rr*3+2]*sMinvp[r*3+2] + Pe[rr];
    }

    // ---- forward sweep: pull joint i's transform via intra-group shuffle ----
    float sacc[7][6];
    float V[6] = {0,0,0,0,0,0};
    float Vd[6];
    Vd[0]=0.f; Vd[1]=0.f; Vd[2]=0.f;
    Vd[3] = is7 ? -sgrav[0] : 0.f;
    Vd[4] = is7 ? -sgrav[1] : 0.f;
    Vd[5] = is7 ? -sgrav[2] : 0.f;
    #pragma unroll
    for (int i=0;i<7;i++){
      float Tl[12];
      #pragma unroll
      for (int k=0;k<12;k++) Tl[k] = __shfl(Tmy[k], i, 8);   // 12 independent bpermutes
      const float* R = Tl;
      const float* p = Tl+9;
      float dqi  = is7 ? dqs[i] : 0.f;
      float ddqi = is7 ? 0.f : ((r==i) ? 1.f : 0.f);
      ad_apply(R,p,V,V);
      #pragma unroll
      for (int k=0;k<6;k++) V[k] += sA[i*6+k]*dqi;
      ad_apply(R,p,Vd,Vd);
      {
        float w0=V[0],w1=V[1],w2=V[2],v0=V[3],v1=V[4],v2=V[5];
        float a0=sA[i*6+0],a1=sA[i*6+1],a2=sA[i*6+2],a3=sA[i*6+3],a4=sA[i*6+4],a5=sA[i*6+5];
        Vd[0] += (w1*a2-w2*a1)*dqi + a0*ddqi;
        Vd[1] += (w2*a0-w0*a2)*dqi + a1*ddqi;
        Vd[2] += (w0*a1-w1*a0)*dqi + a2*ddqi;
        Vd[3] += ((v1*a2-v2*a1)+(w1*a5-w2*a4))*dqi + a3*ddqi;
        Vd[4] += ((v2*a0-v0*a2)+(w2*a3-w0*a5))*dqi + a4*ddqi;
        Vd[5] += ((v0*a1-v1*a0)+(w0*a4-w1*a3))*dqi + a5*ddqi;
      }
      // joint-local G work (symmetric-packed; identical FMA order)
      float gv[6], gvd[6];
      gmatvec2_sym(&sGu[i*21], V, Vd, gv, gvd);
      {
        float w0=V[0],w1=V[1],w2=V[2],v0=V[3],v1=V[4],v2=V[5];
        sacc[i][0] = gvd[0] + (w1*gv[2]-w2*gv[1]) + (v1*gv[5]-v2*gv[4]);
        sacc[i][1] = gvd[1] + (w2*gv[0]-w0*gv[2]) + (v2*gv[3]-v0*gv[5]);
        sacc[i][2] = gvd[2] + (w0*gv[1]-w1*gv[0]) + (v0*gv[4]-v1*gv[3]);
        sacc[i][3] = gvd[3] + (w1*gv[5]-w2*gv[4]);
        sacc[i][4] = gvd[4] + (w2*gv[3]-w0*gv[5]);
        sacc[i][5] = gvd[5] + (w0*gv[4]-w1*gv[3]);
      }
    }

    // ---- backward sweep: transforms re-pulled by shuffle (no LDS) ----
    float m[7];   // lane r<7: row r of symmetric mass matrix ; lane 7: htau
    {
      float F[6];
      #pragma unroll
      for (int k=0;k<6;k++) F[k] = Fend[k];
      #pragma unroll
      for (int i=6;i>=0;i--){
        if (i<6){
          float Tl[12];
          #pragma unroll
          for (int k=0;k<12;k++) Tl[k] = __shfl(Tmy[k], i+1, 8);
          adT_apply(Tl, Tl+9, F, F);
        }
        #pragma unroll
        for (int k=0;k<6;k++) F[k] += sacc[i][k];
        m[i] = F[0]*sA[i*6+0]+F[1]*sA[i*6+1]+F[2]*sA[i*6+2]
             + F[3]*sA[i*6+3]+F[4]*sA[i*6+4]+F[5]*sA[i*6+5];
      }
    }

    // ---- in-register solve (validated round 4) ----
    float U[7][7];   // only j>=i used
    #pragma unroll
    for (int i=0;i<7;i++){
      #pragma unroll
      for (int j=i;j<7;j++) U[i][j] = __shfl(m[j], i, 8);
    }
    float rv[7];
    #pragma unroll
    for (int i=0;i<7;i++) rv[i] = qf[i] - __shfl(m[i], 7, 8);
    #pragma unroll
    for (int k=0;k<7;k++){
      float dinv = frcp(U[k][k]);          // SPD: no pivoting
      #pragma unroll
      for (int i=k+1;i<7;i++){
        float f = U[k][i]*dinv;            // = M[i][k]/d by symmetry
        #pragma unroll
        for (int j=i;j<7;j++) U[i][j] -= f*U[k][j];
        rv[i] -= f*rv[k];
      }
    }
    float x[7];
    #pragma unroll
    for (int i=6;i>=0;i--){
      float s = rv[i];
      #pragma unroll
      for (int j=i+1;j<7;j++) s -= U[i][j]*x[j];
      x[i] = s*frcp(U[i][i]);
    }

    // ---- RK4 bookkeeping (no barrier needed: nothing shared via LDS) ----
    #pragma unroll
    for (int i=0;i<7;i++){
      kq[i]  = dqs[i];
      kdd[i] = x[i];
      accq[i]  += wgt*dqs[i];
      accdq[i] += wgt*x[i];
    }
  }

  // ---- wrap/clip; extract own-joint scalars ----
  float q1r=0.f, dq1r=0.f;
  #pragma unroll
  for (int c=0;c<7;c++){
    float xx = q0[c] + accq[c] + PI_F;
    float mm = xx - floorf(xx * INV_TWO_PI_F) * TWO_PI_F;
    float qv = mm - PI_F;
    float dv = dq0[c] + accdq[c];
    dv = fminf(fmaxf(dv, -MAX_VEL), MAX_VEL);
    q1r  = (r==c) ? qv : q1r;
    dq1r = (r==c) ? dv : dq1r;
  }

  // ---- FK: X_r = M_r exp(A_r q1_r) (lane7: q=0 -> X_7 = M_7 exactly) ----
  float PR[9], Pp[3];
  {
    float Re[9], Pe[3];
    exp_se3_Rp(&sA[ar*6], q1r, Re, Pe);     // q1r==0 for lane 7 -> Re=I, Pe=0
    mul33(&sMR[r*9], Re, PR);
    #pragma unroll
    for (int rr=0;rr<3;rr++)
      Pp[rr] = sMR[r*9+rr*3+0]*Pe[0]+sMR[r*9+rr*3+1]*Pe[1]+sMR[r*9+rr*3+2]*Pe[2] + sMp[r*3+rr];
  }
  // Hillis-Steele inclusive scan over the 8-lane group: P_r = X_0 ... X_r.
  // Same association as the old pairwise tree -> bit-identical lane-7 result.
  #pragma unroll
  for (int d=1; d<8; d<<=1){
    int src = (r>=d) ? (r-d) : 0;
    float Ra[9], pa[3];
    #pragma unroll
    for (int k=0;k<9;k++) Ra[k] = __shfl(PR[k], src, 8);
    #pragma unroll
    for (int k=0;k<3;k++) pa[k] = __shfl(Pp[k], src, 8);
    float Rn[9], pn[3];
    mul33(Ra, PR, Rn);
    #pragma unroll
    for (int rr=0;rr<3;rr++)
      pn[rr] = Ra[rr*3+0]*Pp[0]+Ra[rr*3+1]*Pp[1]+Ra[rr*3+2]*Pp[2] + pa[rr];
    bool use = (r>=d);
    #pragma unroll
    for (int k=0;k<9;k++) PR[k] = use ? Rn[k] : PR[k];
    #pragma unroll
    for (int k=0;k<3;k++) Pp[k] = use ? pn[k] : Pp[k];
  }

  // ---- stores ----
  if (r < 7){
    stv(g_out, b*14+r,   q1r,  isb);
    stv(g_out, b*14+7+r, dq1r, isb);
  } else {
    stv(g_out, B*14 + b*2 + 0, Pp[0], isb);
    stv(g_out, B*14 + b*2 + 1, Pp[1], isb);
  }
}

extern "C" void kernel_launch(void* const* d_in, const int* in_sizes, int n_in,
                              void* d_out, int out_size, void* d_ws, size_t ws_size,
                              hipStream_t stream) {
  const int B = in_sizes[0] / 14;
  const int blocks = (B + 7) / 8;   // 8 elements per 64-thread block
  arm_rk4_kernel<<<blocks, 64, 0, stream>>>(d_in[0], d_in[1], d_in[2], d_in[3],
                                            d_in[4], d_in[5], d_in[6], d_out, B);
}

// Round 6
// 100.736 us; speedup vs baseline: 4.7856x; 4.7856x over previous
//
#include <hip/hip_runtime.h>
#include <hip/hip_bf16.h>

#define DTC 0.1f
#define ACTION_RANGE 50.0f
#define MAX_VEL 20.0f
#define PI_F 3.14159265358979323846f
#define TWO_PI_F 6.28318530717958647692f
#define INV_TWO_PI_F 0.15915494309189533577f

__device__ __forceinline__ float bf2f(__hip_bfloat16 x){ return __bfloat162float(x); }
__device__ __forceinline__ float frcp(float x){ return __builtin_amdgcn_rcpf(x); }

// dtype-dispatched load/store (verified: inputs are bf16, but keep robust)
__device__ __forceinline__ float ldv(const void* p, int i, bool isb){
  return isb ? __bfloat162float(((const __hip_bfloat16*)p)[i]) : ((const float*)p)[i];
}
__device__ __forceinline__ void stv(void* p, int i, float v, bool isb){
  if (isb) ((__hip_bfloat16*)p)[i] = __float2bfloat16(v);
  else     ((float*)p)[i] = v;
}

// Branchless exp(se3): native __sinf/__cosf + Taylor blend.
// Validated rounds 1/2/4: absmax stays at bf16 floor (0.0078125).
__device__ __forceinline__ void exp_se3_Rp(const float* Aj, float s, float* R, float* P){
  float wx=Aj[0]*s, wy=Aj[1]*s, wz=Aj[2]*s;
  float vx=Aj[3]*s, vy=Aj[4]*s, vz=Aj[5]*s;
  float th2 = wx*wx+wy*wy+wz*wz;
  float th = sqrtf(th2);
  float th4 = th2*th2;
  float aS = 1.f - th2*(1.f/6.f)  + th4*(1.f/120.f);
  float bS = 0.5f - th2*(1.f/24.f) + th4*(1.f/720.f);
  float cS = (1.f/6.f) - th2*(1.f/120.f) + th4*(1.f/5040.f);
  float sn = __sinf(th), cs = __cosf(th);
  float inv = frcp(th), inv2 = inv*inv;
  float aL = sn*inv;             // NaN at th=0, selected away
  float bL = (1.f-cs)*inv2;
  float cL = (th-sn)*inv2*inv;
  bool sm = th < 0.25f;
  float a = sm?aS:aL, b = sm?bS:bL, c = sm?cS:cL;
  R[0]=1.f+b*(wx*wx-th2); R[1]=b*wx*wy-a*wz;      R[2]=b*wx*wz+a*wy;
  R[3]=b*wx*wy+a*wz;      R[4]=1.f+b*(wy*wy-th2); R[5]=b*wy*wz-a*wx;
  R[6]=b*wx*wz-a*wy;      R[7]=b*wy*wz+a*wx;      R[8]=1.f+b*(wz*wz-th2);
  float V0=1.f+c*(wx*wx-th2), V1=c*wx*wy-b*wz,      V2=c*wx*wz+b*wy;
  float V3=c*wx*wy+b*wz,      V4=1.f+c*(wy*wy-th2), V5=c*wy*wz-b*wx;
  float V6=c*wx*wz-b*wy,      V7=c*wy*wz+b*wx,      V8=1.f+c*(wz*wz-th2);
  P[0]=V0*vx+V1*vy+V2*vz;
  P[1]=V3*vx+V4*vy+V5*vz;
  P[2]=V6*vx+V7*vy+V8*vz;
}

__device__ __forceinline__ void mul33(const float* X, const float* Y, float* Z){
  #pragma unroll
  for (int r=0;r<3;r++){
    float x0=X[r*3+0], x1=X[r*3+1], x2=X[r*3+2];
    Z[r*3+0]=x0*Y[0]+x1*Y[3]+x2*Y[6];
    Z[r*3+1]=x0*Y[1]+x1*Y[4]+x2*Y[7];
    Z[r*3+2]=x0*Y[2]+x1*Y[5]+x2*Y[8];
  }
}

// V' = Ad(T) V (alias-safe)
__device__ __forceinline__ void ad_apply(const float* R, const float* p, const float* Vin, float* Vout){
  float i0=Vin[0],i1=Vin[1],i2=Vin[2],i3=Vin[3],i4=Vin[4],i5=Vin[5];
  float w0 = R[0]*i0+R[1]*i1+R[2]*i2;
  float w1 = R[3]*i0+R[4]*i1+R[5]*i2;
  float w2 = R[6]*i0+R[7]*i1+R[8]*i2;
  float r0 = R[0]*i3+R[1]*i4+R[2]*i5;
  float r1 = R[3]*i3+R[4]*i4+R[5]*i5;
  float r2 = R[6]*i3+R[7]*i4+R[8]*i5;
  float p0=p[0],p1=p[1],p2=p[2];
  Vout[0]=w0; Vout[1]=w1; Vout[2]=w2;
  Vout[3]=p1*w2-p2*w1+r0;
  Vout[4]=p2*w0-p0*w2+r1;
  Vout[5]=p0*w1-p1*w0+r2;
}

// F' = Ad(T)^T F (alias-safe)
__device__ __forceinline__ void adT_apply(const float* R, const float* p, const float* Fin, float* Fout){
  float m0=Fin[0],m1=Fin[1],m2=Fin[2],f0=Fin[3],f1=Fin[4],f2=Fin[5];
  float p0=p[0],p1=p[1],p2=p[2];
  float cx = m0 - (p1*f2 - p2*f1);
  float cy = m1 - (p2*f0 - p0*f2);
  float cz = m2 - (p0*f1 - p1*f0);
  float o0 = R[0]*cx + R[3]*cy + R[6]*cz;
  float o1 = R[1]*cx + R[4]*cy + R[7]*cz;
  float o2 = R[2]*cx + R[5]*cy + R[8]*cz;
  float o3 = R[0]*f0 + R[3]*f1 + R[6]*f2;
  float o4 = R[1]*f0 + R[4]*f1 + R[7]*f2;
  float o5 = R[2]*f0 + R[5]*f1 + R[8]*f2;
  Fout[0]=o0;Fout[1]=o1;Fout[2]=o2;Fout[3]=o3;Fout[4]=o4;Fout[5]=o5;
}

// Both G-matvecs from symmetric-packed Gu (21 floats, stride-24 rows in LDS).
// Same per-row FMA order (c=0..5) as the dense version -> bit-identical.
// Numerically validated round 5 (absmax at bf16 floor).
__device__ __forceinline__ void gmatvec2_sym(const float* Gu, const float* v, const float* d,
                                             float* gv, float* gvd){
  float g0=Gu[0],g1=Gu[1],g2=Gu[2],g3=Gu[3],g4=Gu[4],g5=Gu[5];
  float g6=Gu[6],g7=Gu[7],g8=Gu[8],g9=Gu[9],g10=Gu[10];
  float g11=Gu[11],g12=Gu[12],g13=Gu[13],g14=Gu[14];
  float g15=Gu[15],g16=Gu[16],g17=Gu[17],g18=Gu[18],g19=Gu[19],g20=Gu[20];
  gv[0]=g0*v[0]+g1 *v[1]+g2 *v[2]+g3 *v[3]+g4 *v[4]+g5 *v[5];
  gv[1]=g1*v[0]+g6 *v[1]+g7 *v[2]+g8 *v[3]+g9 *v[4]+g10*v[5];
  gv[2]=g2*v[0]+g7 *v[1]+g11*v[2]+g12*v[3]+g13*v[4]+g14*v[5];
  gv[3]=g3*v[0]+g8 *v[1]+g12*v[2]+g15*v[3]+g16*v[4]+g17*v[5];
  gv[4]=g4*v[0]+g9 *v[1]+g13*v[2]+g16*v[3]+g18*v[4]+g19*v[5];
  gv[5]=g5*v[0]+g10*v[1]+g14*v[2]+g17*v[3]+g19*v[4]+g20*v[5];
  gvd[0]=g0*d[0]+g1 *d[1]+g2 *d[2]+g3 *d[3]+g4 *d[4]+g5 *d[5];
  gvd[1]=g1*d[0]+g6 *d[1]+g7 *d[2]+g8 *d[3]+g9 *d[4]+g10*d[5];
  gvd[2]=g2*d[0]+g7 *d[1]+g11*d[2]+g12*d[3]+g13*d[4]+g14*d[5];
  gvd[3]=g3*d[0]+g8 *d[1]+g12*d[2]+g15*d[3]+g16*d[4]+g17*d[5];
  gvd[4]=g4*d[0]+g9 *d[1]+g13*d[2]+g16*d[3]+g18*d[4]+g19*d[5];
  gvd[5]=g5*d[0]+g10*d[1]+g14*d[2]+g17*d[3]+g19*d[4]+g20*d[5];
}

// per-element LDS work stride.
// 100: e*400 bytes -> 16B-aligned base (W transforms at r*48 B also 16B-aligned
// => contiguous 12-float groups are ds_read_b128/ds_write_b128 merge-eligible),
// AND e*100 mod 32 = e*4 -> element-groups sit on distinct bank offsets.
#define W_STRIDE 100

__global__ __launch_bounds__(64) void arm_rk4_kernel(
    const void* __restrict__ g_state,
    const void* __restrict__ g_torque,
    const void* __restrict__ g_M,
    const void* __restrict__ g_A,
    const void* __restrict__ g_L,
    const void* __restrict__ g_grav,
    const void* __restrict__ g_ftip,
    void* __restrict__ g_out,
    int B)
{
  __shared__ float sA[42];                     // A[7][6]
  __shared__ __align__(16) float sGu[168];     // G sym-packed 21/joint, stride 24 (rows 16B-aligned)
  __shared__ float sMinvR[72];   // inv(M_i): R^T, i=0..7
  __shared__ float sMinvp[24];   //            -R^T p
  __shared__ float sMR[72];      // M_i rotation (FK)
  __shared__ float sMp[24];      // M_i translation
  __shared__ float sgrav[3];
  __shared__ float sftip[6];
  __shared__ __align__(16) float sW[8*W_STRIDE];

  const bool isb = fabsf(bf2f(((const __hip_bfloat16*)g_grav)[1]) + 9.8f) < 0.5f;

  const int t = threadIdx.x;
  for (int x=t; x<42; x+=64) sA[x] = ldv(g_A, x, isb);
  for (int x=t; x<168; x+=64){
    int i = x/24; int u = x - i*24;
    if (u < 21){
      int rr = 0, u2 = u;
      while (u2 >= 6-rr){ u2 -= 6-rr; rr++; }   // init-only scalar loop
      int cc = rr + u2;
      float s = 0.f;
      #pragma unroll
      for (int k=0;k<6;k++) s += ldv(g_L, i*36+rr*6+k, isb) * ldv(g_L, i*36+cc*6+k, isb);
      sGu[x] = s;
    } else {
      sGu[x] = 0.f;                             // pad
    }
  }
  if (t < 8){
    float R[9], p[3];
    #pragma unroll
    for (int rr=0;rr<3;rr++){
      #pragma unroll
      for (int cc=0;cc<3;cc++) R[rr*3+cc] = ldv(g_M, t*16 + rr*4 + cc, isb);
      p[rr] = ldv(g_M, t*16 + rr*4 + 3, isb);
    }
    #pragma unroll
    for (int rr=0;rr<3;rr++){
      #pragma unroll
      for (int cc=0;cc<3;cc++){ sMR[t*9+rr*3+cc] = R[rr*3+cc]; sMinvR[t*9+rr*3+cc] = R[cc*3+rr]; }
      sMp[t*3+rr] = p[rr];
      sMinvp[t*3+rr] = -(R[0*3+rr]*p[0] + R[1*3+rr]*p[1] + R[2*3+rr]*p[2]);
    }
  }
  if (t == 0){ for (int k=0;k<3;k++) sgrav[k] = ldv(g_grav, k, isb); }
  if (t == 1){ for (int k=0;k<6;k++) sftip[k] = ldv(g_ftip, k, isb); }
  __syncthreads();

  const int e = t >> 3;          // element within block (0..7)
  const int r = t & 7;           // role: 0..6 = mass row/col r ; 7 = bias torque h
  int b = blockIdx.x * 8 + e;
  if (b >= B) b = B - 1;         // safe clamp (B divisible by 8 in practice)
  const bool is7 = (r == 7);
  float* W = &sW[e*W_STRIDE];

  // replicated per-element state
  float q0[7], dq0[7], qf[7];
  #pragma unroll
  for (int i=0;i<7;i++){
    q0[i]  = ldv(g_state, b*14+i, isb);
    dq0[i] = ldv(g_state, b*14+7+i, isb);
    qf[i]  = ldv(g_torque, b*7+i, isb) * ACTION_RANGE;
  }
  float kq[7], kdd[7], accq[7], accdq[7];
  #pragma unroll
  for (int i=0;i<7;i++){ kq[i]=0.f; kdd[i]=0.f; accq[i]=0.f; accdq[i]=0.f; }

  // role-dependent tip wrench (constant across stages): role7 gets AdT_end^T ftip
  float Fend[6];
  {
    float tf[6]; adT_apply(&sMinvR[63], &sMinvp[21], sftip, tf);
    #pragma unroll
    for (int k=0;k<6;k++) Fend[k] = is7 ? tf[k] : 0.f;
  }

  #pragma unroll 1
  for (int st=0; st<4; ++st){
    const float cin = (st==0) ? 0.f : ((st==3) ? DTC : 0.5f*DTC);
    const float wgt = (st==0||st==3) ? (DTC/6.f) : (DTC/3.f);
    float qs[7], dqs[7];
    #pragma unroll
    for (int i=0;i<7;i++){ qs[i]=q0[i]+cin*kq[i]; dqs[i]=dq0[i]+cin*kdd[i]; }

    // own joint angle (scalar extraction, no runtime register indexing)
    float qsr = 0.f;
    #pragma unroll
    for (int c=0;c<7;c++) qsr = (r==c) ? qs[c] : qsr;

    // ---- transforms: lane r<7 computes T_r = exp(-A_r q_r) inv(M_r) -> LDS ----
    if (r < 7){
      float Re[9], Pe[3], Rt[9];
      exp_se3_Rp(&sA[r*6], -qsr, Re, Pe);
      mul33(Re, &sMinvR[r*9], Rt);
      float Tw[12];
      #pragma unroll
      for (int k=0;k<9;k++) Tw[k] = Rt[k];
      #pragma unroll
      for (int rr=0;rr<3;rr++)
        Tw[9+rr] = Re[rr*3+0]*sMinvp[r*3+0] + Re[rr*3+1]*sMinvp[r*3+1]
                 + Re[rr*3+2]*sMinvp[r*3+2] + Pe[rr];
      #pragma unroll
      for (int k=0;k<12;k++) W[r*12+k] = Tw[k];   // contiguous + 16B-aligned: b128 merge
    }
    __syncthreads();

    // ---- forward sweep (all 64 lanes, uniform code) ----
    // role r<7: dq=0, ddq=e_r, g=0   -> mass row r pieces
    // role 7 : dq=dqs, ddq=0, g=grav -> bias pieces
    // G-multiplies + cross terms are joint-local -> computed here and stored as
    // sacc_i (6 floats/joint); backward sweep has no G on its chain (r4-validated).
    float sacc[7][6];
    float V[6] = {0,0,0,0,0,0};
    float Vd[6];
    Vd[0]=0.f; Vd[1]=0.f; Vd[2]=0.f;
    Vd[3] = is7 ? -sgrav[0] : 0.f;
    Vd[4] = is7 ? -sgrav[1] : 0.f;
    Vd[5] = is7 ? -sgrav[2] : 0.f;
    #pragma unroll
    for (int i=0;i<7;i++){
      float Tl[12];                         // one 12-float LDS pull per joint
      #pragma unroll
      for (int k=0;k<12;k++) Tl[k] = W[i*12+k];
      const float* R = Tl;
      const float* p = Tl+9;
      float dqi  = is7 ? dqs[i] : 0.f;
      float ddqi = is7 ? 0.f : ((r==i) ? 1.f : 0.f);
      ad_apply(R,p,V,V);
      #pragma unroll
      for (int k=0;k<6;k++) V[k] += sA[i*6+k]*dqi;
      ad_apply(R,p,Vd,Vd);
      {
        float w0=V[0],w1=V[1],w2=V[2],v0=V[3],v1=V[4],v2=V[5];
        float a0=sA[i*6+0],a1=sA[i*6+1],a2=sA[i*6+2],a3=sA[i*6+3],a4=sA[i*6+4],a5=sA[i*6+5];
        Vd[0] += (w1*a2-w2*a1)*dqi + a0*ddqi;
        Vd[1] += (w2*a0-w0*a2)*dqi + a1*ddqi;
        Vd[2] += (w0*a1-w1*a0)*dqi + a2*ddqi;
        Vd[3] += ((v1*a2-v2*a1)+(w1*a5-w2*a4))*dqi + a3*ddqi;
        Vd[4] += ((v2*a0-v0*a2)+(w2*a3-w0*a5))*dqi + a4*ddqi;
        Vd[5] += ((v0*a1-v1*a0)+(w0*a4-w1*a3))*dqi + a5*ddqi;
      }
      // joint-local G work (symmetric-packed; identical FMA order)
      float gv[6], gvd[6];
      gmatvec2_sym(&sGu[i*24], V, Vd, gv, gvd);
      {
        float w0=V[0],w1=V[1],w2=V[2],v0=V[3],v1=V[4],v2=V[5];
        sacc[i][0] = gvd[0] + (w1*gv[2]-w2*gv[1]) + (v1*gv[5]-v2*gv[4]);
        sacc[i][1] = gvd[1] + (w2*gv[0]-w0*gv[2]) + (v2*gv[3]-v0*gv[5]);
        sacc[i][2] = gvd[2] + (w0*gv[1]-w1*gv[0]) + (v0*gv[4]-v1*gv[3]);
        sacc[i][3] = gvd[3] + (w1*gv[5]-w2*gv[4]);
        sacc[i][4] = gvd[4] + (w2*gv[3]-w0*gv[5]);
        sacc[i][5] = gvd[5] + (w0*gv[4]-w1*gv[3]);
      }
    }

    // ---- backward sweep: pure-register except W/A reads ----
    float m[7];   // lane r<7: row r of symmetric mass matrix ; lane 7: htau
    {
      float F[6];
      #pragma unroll
      for (int k=0;k<6;k++) F[k] = Fend[k];
      #pragma unroll
      for (int i=6;i>=0;i--){
        if (i<6){
          float Tl[12];
          #pragma unroll
          for (int k=0;k<12;k++) Tl[k] = W[(i+1)*12+k];
          adT_apply(Tl, Tl+9, F, F);
        }
        #pragma unroll
        for (int k=0;k<6;k++) F[k] += sacc[i][k];
        m[i] = F[0]*sA[i*6+0]+F[1]*sA[i*6+1]+F[2]*sA[i*6+2]
             + F[3]*sA[i*6+3]+F[4]*sA[i*6+4]+F[5]*sA[i*6+5];
      }
    }

    // ---- in-register solve (validated rounds 0/4) ----
    // lane i holds column i == row i (symmetry). ONE batch of 35 independent
    // gathers, then symmetric GE with frcp; all 8 lanes compute identical x[].
    float U[7][7];   // only j>=i used; trailing blocks stay symmetric under GE
    #pragma unroll
    for (int i=0;i<7;i++){
      #pragma unroll
      for (int j=i;j<7;j++) U[i][j] = __shfl(m[j], i, 8);
    }
    float rv[7];
    #pragma unroll
    for (int i=0;i<7;i++) rv[i] = qf[i] - __shfl(m[i], 7, 8);
    #pragma unroll
    for (int k=0;k<7;k++){
      float dinv = frcp(U[k][k]);          // SPD: no pivoting
      #pragma unroll
      for (int i=k+1;i<7;i++){
        float f = U[k][i]*dinv;            // = M[i][k]/d by symmetry
        #pragma unroll
        for (int j=i;j<7;j++) U[i][j] -= f*U[k][j];
        rv[i] -= f*rv[k];
      }
    }
    float x[7];
    #pragma unroll
    for (int i=6;i>=0;i--){
      float s = rv[i];
      #pragma unroll
      for (int j=i+1;j<7;j++) s -= U[i][j]*x[j];
      x[i] = s*frcp(U[i][i]);
    }

    // ---- RK4 bookkeeping (every lane has the full solution) ----
    #pragma unroll
    for (int i=0;i<7;i++){
      kq[i]  = dqs[i];
      kdd[i] = x[i];
      accq[i]  += wgt*dqs[i];
      accdq[i] += wgt*x[i];
    }
    __syncthreads();  // protect W before next stage's transform writes
  }

  // ---- wrap/clip; extract own-joint scalars (no runtime reg indexing) ----
  float q1r=0.f, dq1r=0.f;
  #pragma unroll
  for (int c=0;c<7;c++){
    float xx = q0[c] + accq[c] + PI_F;
    float mm = xx - floorf(xx * INV_TWO_PI_F) * TWO_PI_F;
    float qv = mm - PI_F;
    float dv = dq0[c] + accdq[c];
    dv = fminf(fmaxf(dv, -MAX_VEL), MAX_VEL);
    q1r  = (r==c) ? qv : q1r;
    dq1r = (r==c) ? dv : dq1r;
  }

  // ---- FK tree: X_r = M_r exp(A_r q1_r) (r<7), X_7 = M_7 ; product left-to-right ----
  {
    float XR[9], Xp[3];
    if (r < 7){
      float Re[9], Pe[3];
      exp_se3_Rp(&sA[r*6], q1r, Re, Pe);
      mul33(&sMR[r*9], Re, XR);
      #pragma unroll
      for (int rr=0;rr<3;rr++)
        Xp[rr] = sMR[r*9+rr*3+0]*Pe[0]+sMR[r*9+rr*3+1]*Pe[1]+sMR[r*9+rr*3+2]*Pe[2] + sMp[r*3+rr];
    } else {
      #pragma unroll
      for (int k=0;k<9;k++) XR[k] = sMR[63+k];
      #pragma unroll
      for (int k=0;k<3;k++) Xp[k] = sMp[21+k];
    }
    #pragma unroll
    for (int k=0;k<9;k++) W[r*12+k]   = XR[k];
    #pragma unroll
    for (int k=0;k<3;k++) W[r*12+9+k] = Xp[k];
  }
  __syncthreads();

  #pragma unroll
  for (int w=4; w>=1; w>>=1){
    float Ra[9], pa[3], Rb[9], pb[3];
    if (r < w){
      #pragma unroll
      for (int k=0;k<9;k++){ Ra[k]=W[(2*r)*12+k]; Rb[k]=W[(2*r+1)*12+k]; }
      #pragma unroll
      for (int k=0;k<3;k++){ pa[k]=W[(2*r)*12+9+k]; pb[k]=W[(2*r+1)*12+9+k]; }
    }
    __syncthreads();
    if (r < w){
      float Rc[9];
      mul33(Ra, Rb, Rc);
      #pragma unroll
      for (int k=0;k<9;k++) W[r*12+k] = Rc[k];
      #pragma unroll
      for (int rr=0;rr<3;rr++)
        W[r*12+9+rr] = Ra[rr*3+0]*pb[0]+Ra[rr*3+1]*pb[1]+Ra[rr*3+2]*pb[2] + pa[rr];
    }
    __syncthreads();
  }

  // ---- stores ----
  if (r < 7){
    stv(g_out, b*14+r,   q1r,  isb);
    stv(g_out, b*14+7+r, dq1r, isb);
  } else {
    stv(g_out, B*14 + b*2 + 0, W[9],  isb);
    stv(g_out, B*14 + b*2 + 1, W[10], isb);
  }
}

extern "C" void kernel_launch(void* const* d_in, const int* in_sizes, int n_in,
                              void* d_out, int out_size, void* d_ws, size_t ws_size,
                              hipStream_t stream) {
  const int B = in_sizes[0] / 14;
  const int blocks = (B + 7) / 8;   // 8 elements per 64-thread block
  arm_rk4_kernel<<<blocks, 64, 0, stream>>>(d_in[0], d_in[1], d_in[2], d_in[3],
                                            d_in[4], d_in[5], d_in[6], d_out, B);
}

// Round 7
// 96.466 us; speedup vs baseline: 4.9974x; 1.0443x over previous
//
#include <hip/hip_runtime.h>
#include <hip/hip_bf16.h>

#define DTC 0.1f
#define ACTION_RANGE 50.0f
#define MAX_VEL 20.0f
#define PI_F 3.14159265358979323846f
#define TWO_PI_F 6.28318530717958647692f
#define INV_TWO_PI_F 0.15915494309189533577f

__device__ __forceinline__ float bf2f(__hip_bfloat16 x){ return __bfloat162float(x); }
__device__ __forceinline__ float frcp(float x){ return __builtin_amdgcn_rcpf(x); }

__device__ __forceinline__ float ldv(const void* p, int i, bool isb){
  return isb ? __bfloat162float(((const __hip_bfloat16*)p)[i]) : ((const float*)p)[i];
}
__device__ __forceinline__ void stv(void* p, int i, float v, bool isb){
  if (isb) ((__hip_bfloat16*)p)[i] = __float2bfloat16(v);
  else     ((float*)p)[i] = v;
}

// Branchless exp(se3): native __sinf/__cosf + Taylor blend (validated r1/2/4/6).
__device__ __forceinline__ void exp_se3_Rp(const float* Aj, float s, float* R, float* P){
  float wx=Aj[0]*s, wy=Aj[1]*s, wz=Aj[2]*s;
  float vx=Aj[3]*s, vy=Aj[4]*s, vz=Aj[5]*s;
  float th2 = wx*wx+wy*wy+wz*wz;
  float th = sqrtf(th2);
  float th4 = th2*th2;
  float aS = 1.f - th2*(1.f/6.f)  + th4*(1.f/120.f);
  float bS = 0.5f - th2*(1.f/24.f) + th4*(1.f/720.f);
  float cS = (1.f/6.f) - th2*(1.f/120.f) + th4*(1.f/5040.f);
  float sn = __sinf(th), cs = __cosf(th);
  float inv = frcp(th), inv2 = inv*inv;
  float aL = sn*inv;
  float bL = (1.f-cs)*inv2;
  float cL = (th-sn)*inv2*inv;
  bool sm = th < 0.25f;
  float a = sm?aS:aL, b = sm?bS:bL, c = sm?cS:cL;
  R[0]=1.f+b*(wx*wx-th2); R[1]=b*wx*wy-a*wz;      R[2]=b*wx*wz+a*wy;
  R[3]=b*wx*wy+a*wz;      R[4]=1.f+b*(wy*wy-th2); R[5]=b*wy*wz-a*wx;
  R[6]=b*wx*wz-a*wy;      R[7]=b*wy*wz+a*wx;      R[8]=1.f+b*(wz*wz-th2);
  float V0=1.f+c*(wx*wx-th2), V1=c*wx*wy-b*wz,      V2=c*wx*wz+b*wy;
  float V3=c*wx*wy+b*wz,      V4=1.f+c*(wy*wy-th2), V5=c*wy*wz-b*wx;
  float V6=c*wx*wz-b*wy,      V7=c*wy*wz+b*wx,      V8=1.f+c*(wz*wz-th2);
  P[0]=V0*vx+V1*vy+V2*vz;
  P[1]=V3*vx+V4*vy+V5*vz;
  P[2]=V6*vx+V7*vy+V8*vz;
}

__device__ __forceinline__ void mul33(const float* X, const float* Y, float* Z){
  #pragma unroll
  for (int r=0;r<3;r++){
    float x0=X[r*3+0], x1=X[r*3+1], x2=X[r*3+2];
    Z[r*3+0]=x0*Y[0]+x1*Y[3]+x2*Y[6];
    Z[r*3+1]=x0*Y[1]+x1*Y[4]+x2*Y[7];
    Z[r*3+2]=x0*Y[2]+x1*Y[5]+x2*Y[8];
  }
}

__device__ __forceinline__ void ad_apply(const float* R, const float* p, const float* Vin, float* Vout){
  float i0=Vin[0],i1=Vin[1],i2=Vin[2],i3=Vin[3],i4=Vin[4],i5=Vin[5];
  float w0 = R[0]*i0+R[1]*i1+R[2]*i2;
  float w1 = R[3]*i0+R[4]*i1+R[5]*i2;
  float w2 = R[6]*i0+R[7]*i1+R[8]*i2;
  float r0 = R[0]*i3+R[1]*i4+R[2]*i5;
  float r1 = R[3]*i3+R[4]*i4+R[5]*i5;
  float r2 = R[6]*i3+R[7]*i4+R[8]*i5;
  float p0=p[0],p1=p[1],p2=p[2];
  Vout[0]=w0; Vout[1]=w1; Vout[2]=w2;
  Vout[3]=p1*w2-p2*w1+r0;
  Vout[4]=p2*w0-p0*w2+r1;
  Vout[5]=p0*w1-p1*w0+r2;
}

__device__ __forceinline__ void adT_apply(const float* R, const float* p, const float* Fin, float* Fout){
  float m0=Fin[0],m1=Fin[1],m2=Fin[2],f0=Fin[3],f1=Fin[4],f2=Fin[5];
  float p0=p[0],p1=p[1],p2=p[2];
  float cx = m0 - (p1*f2 - p2*f1);
  float cy = m1 - (p2*f0 - p0*f2);
  float cz = m2 - (p0*f1 - p1*f0);
  float o0 = R[0]*cx + R[3]*cy + R[6]*cz;
  float o1 = R[1]*cx + R[4]*cy + R[7]*cz;
  float o2 = R[2]*cx + R[5]*cy + R[8]*cz;
  float o3 = R[0]*f0 + R[3]*f1 + R[6]*f2;
  float o4 = R[1]*f0 + R[4]*f1 + R[7]*f2;
  float o5 = R[2]*f0 + R[5]*f1 + R[8]*f2;
  Fout[0]=o0;Fout[1]=o1;Fout[2]=o2;Fout[3]=o3;Fout[4]=o4;Fout[5]=o5;
}

// Both G-matvecs from symmetric-packed Gu (validated r6; identical FMA order).
__device__ __forceinline__ void gmatvec2_sym(const float* Gu, const float* v, const float* d,
                                             float* gv, float* gvd){
  float g0=Gu[0],g1=Gu[1],g2=Gu[2],g3=Gu[3],g4=Gu[4],g5=Gu[5];
  float g6=Gu[6],g7=Gu[7],g8=Gu[8],g9=Gu[9],g10=Gu[10];
  float g11=Gu[11],g12=Gu[12],g13=Gu[13],g14=Gu[14];
  float g15=Gu[15],g16=Gu[16],g17=Gu[17],g18=Gu[18],g19=Gu[19],g20=Gu[20];
  gv[0]=g0*v[0]+g1 *v[1]+g2 *v[2]+g3 *v[3]+g4 *v[4]+g5 *v[5];
  gv[1]=g1*v[0]+g6 *v[1]+g7 *v[2]+g8 *v[3]+g9 *v[4]+g10*v[5];
  gv[2]=g2*v[0]+g7 *v[1]+g11*v[2]+g12*v[3]+g13*v[4]+g14*v[5];
  gv[3]=g3*v[0]+g8 *v[1]+g12*v[2]+g15*v[3]+g16*v[4]+g17*v[5];
  gv[4]=g4*v[0]+g9 *v[1]+g13*v[2]+g16*v[3]+g18*v[4]+g19*v[5];
  gv[5]=g5*v[0]+g10*v[1]+g14*v[2]+g17*v[3]+g19*v[4]+g20*v[5];
  gvd[0]=g0*d[0]+g1 *d[1]+g2 *d[2]+g3 *d[3]+g4 *d[4]+g5 *d[5];
  gvd[1]=g1*d[0]+g6 *d[1]+g7 *d[2]+g8 *d[3]+g9 *d[4]+g10*d[5];
  gvd[2]=g2*d[0]+g7 *d[1]+g11*d[2]+g12*d[3]+g13*d[4]+g14*d[5];
  gvd[3]=g3*d[0]+g8 *d[1]+g12*d[2]+g15*d[3]+g16*d[4]+g17*d[5];
  gvd[4]=g4*d[0]+g9 *d[1]+g13*d[2]+g16*d[3]+g18*d[4]+g19*d[5];
  gvd[5]=g5*d[0]+g10*d[1]+g14*d[2]+g17*d[3]+g19*d[4]+g20*d[5];
}

#define W_STRIDE 100   // e*400B and r*48B both 16B-aligned -> b128 merges

__global__ __launch_bounds__(64) void arm_rk4_kernel(
    const void* __restrict__ g_state,
    const void* __restrict__ g_torque,
    const void* __restrict__ g_M,
    const void* __restrict__ g_A,
    const void* __restrict__ g_L,
    const void* __restrict__ g_grav,
    const void* __restrict__ g_ftip,
    void* __restrict__ g_out,
    int B)
{
  __shared__ __align__(16) float sA8[56];     // A[7][8] padded -> 32B rows, b128-merge
  __shared__ __align__(16) float sGu[168];    // G sym-packed, stride 24 (16B-aligned rows)
  __shared__ float sMinvR[72];
  __shared__ float sMinvp[24];
  __shared__ float sMR[72];
  __shared__ float sMp[24];
  __shared__ float sgrav[3];
  __shared__ float sftip[6];
  __shared__ __align__(16) float sW[8*W_STRIDE];
  // Rolled-loop spill targets (rule #20: no runtime-indexed register arrays).
  __shared__ float sacc_lds[7*6*64];  // [joint][k][lane]  lane-contiguous, conflict-free
  __shared__ float m_lds[7*64];       // [joint][lane]
  __shared__ float dqs_lds[7*8];      // [joint][element]

  const bool isb = fabsf(bf2f(((const __hip_bfloat16*)g_grav)[1]) + 9.8f) < 0.5f;

  const int t = threadIdx.x;
  for (int x=t; x<56; x+=64){
    int i = x >> 3, k = x & 7;
    sA8[x] = (k < 6) ? ldv(g_A, i*6+k, isb) : 0.f;
  }
  for (int x=t; x<168; x+=64){
    int i = x/24; int u = x - i*24;
    if (u < 21){
      int rr = 0, u2 = u;
      while (u2 >= 6-rr){ u2 -= 6-rr; rr++; }   // init-only
      int cc = rr + u2;
      float s = 0.f;
      #pragma unroll
      for (int k=0;k<6;k++) s += ldv(g_L, i*36+rr*6+k, isb) * ldv(g_L, i*36+cc*6+k, isb);
      sGu[x] = s;
    } else sGu[x] = 0.f;
  }
  if (t < 8){
    float R[9], p[3];
    #pragma unroll
    for (int rr=0;rr<3;rr++){
      #pragma unroll
      for (int cc=0;cc<3;cc++) R[rr*3+cc] = ldv(g_M, t*16 + rr*4 + cc, isb);
      p[rr] = ldv(g_M, t*16 + rr*4 + 3, isb);
    }
    #pragma unroll
    for (int rr=0;rr<3;rr++){
      #pragma unroll
      for (int cc=0;cc<3;cc++){ sMR[t*9+rr*3+cc] = R[rr*3+cc]; sMinvR[t*9+rr*3+cc] = R[cc*3+rr]; }
      sMp[t*3+rr] = p[rr];
      sMinvp[t*3+rr] = -(R[0*3+rr]*p[0] + R[1*3+rr]*p[1] + R[2*3+rr]*p[2]);
    }
  }
  if (t == 0){ for (int k=0;k<3;k++) sgrav[k] = ldv(g_grav, k, isb); }
  if (t == 1){ for (int k=0;k<6;k++) sftip[k] = ldv(g_ftip, k, isb); }
  __syncthreads();

  const int e = t >> 3;
  const int r = t & 7;
  int b = blockIdx.x * 8 + e;
  if (b >= B) b = B - 1;
  const bool is7 = (r == 7);
  float* W = &sW[e*W_STRIDE];

  float q0[7], dq0[7], qf[7];
  #pragma unroll
  for (int i=0;i<7;i++){
    q0[i]  = ldv(g_state, b*14+i, isb);
    dq0[i] = ldv(g_state, b*14+7+i, isb);
    qf[i]  = ldv(g_torque, b*7+i, isb) * ACTION_RANGE;
  }
  float kq[7], kdd[7], accq[7], accdq[7];
  #pragma unroll
  for (int i=0;i<7;i++){ kq[i]=0.f; kdd[i]=0.f; accq[i]=0.f; accdq[i]=0.f; }

  float Fend[6];
  {
    float tf[6]; adT_apply(&sMinvR[63], &sMinvp[21], sftip, tf);
    #pragma unroll
    for (int k=0;k<6;k++) Fend[k] = is7 ? tf[k] : 0.f;
  }

  #pragma unroll 1
  for (int st=0; st<4; ++st){
    const float cin = (st==0) ? 0.f : ((st==3) ? DTC : 0.5f*DTC);
    const float wgt = (st==0||st==3) ? (DTC/6.f) : (DTC/3.f);
    float qs[7], dqs[7];
    #pragma unroll
    for (int i=0;i<7;i++){ qs[i]=q0[i]+cin*kq[i]; dqs[i]=dq0[i]+cin*kdd[i]; }

    float qsr = 0.f;
    #pragma unroll
    for (int c=0;c<7;c++) qsr = (r==c) ? qs[c] : qsr;

    // lane 7 publishes dqs for its group (read in the rolled fwd loop)
    if (is7){
      #pragma unroll
      for (int i=0;i<7;i++) dqs_lds[i*8+e] = dqs[i];
    }

    // ---- transforms (unrolled, per-lane) -> W ----
    if (r < 7){
      float Re[9], Pe[3], Rt[9];
      exp_se3_Rp(&sA8[r*8], -qsr, Re, Pe);
      mul33(Re, &sMinvR[r*9], Rt);
      float Tw[12];
      #pragma unroll
      for (int k=0;k<9;k++) Tw[k] = Rt[k];
      #pragma unroll
      for (int rr=0;rr<3;rr++)
        Tw[9+rr] = Re[rr*3+0]*sMinvp[r*3+0] + Re[rr*3+1]*sMinvp[r*3+1]
                 + Re[rr*3+2]*sMinvp[r*3+2] + Pe[rr];
      #pragma unroll
      for (int k=0;k<12;k++) W[r*12+k] = Tw[k];
    }
    __syncthreads();

    // ---- forward sweep: ROLLED (I$-footprint experiment) ----
    float V[6] = {0,0,0,0,0,0};
    float Vd[6];
    Vd[0]=0.f; Vd[1]=0.f; Vd[2]=0.f;
    Vd[3] = is7 ? -sgrav[0] : 0.f;
    Vd[4] = is7 ? -sgrav[1] : 0.f;
    Vd[5] = is7 ? -sgrav[2] : 0.f;
    #pragma unroll 1
    for (int i=0;i<7;i++){
      float Tl[12];
      #pragma unroll
      for (int k=0;k<12;k++) Tl[k] = W[i*12+k];
      float Al[6];
      #pragma unroll
      for (int k=0;k<6;k++) Al[k] = sA8[i*8+k];
      float dqi  = is7 ? dqs_lds[i*8+e] : 0.f;
      float ddqi = (!is7 && r==i) ? 1.f : 0.f;
      ad_apply(Tl, Tl+9, V, V);
      #pragma unroll
      for (int k=0;k<6;k++) V[k] += Al[k]*dqi;
      ad_apply(Tl, Tl+9, Vd, Vd);
      {
        float w0=V[0],w1=V[1],w2=V[2],v0=V[3],v1=V[4],v2=V[5];
        Vd[0] += (w1*Al[2]-w2*Al[1])*dqi + Al[0]*ddqi;
        Vd[1] += (w2*Al[0]-w0*Al[2])*dqi + Al[1]*ddqi;
        Vd[2] += (w0*Al[1]-w1*Al[0])*dqi + Al[2]*ddqi;
        Vd[3] += ((v1*Al[2]-v2*Al[1])+(w1*Al[5]-w2*Al[4]))*dqi + Al[3]*ddqi;
        Vd[4] += ((v2*Al[0]-v0*Al[2])+(w2*Al[3]-w0*Al[5]))*dqi + Al[4]*ddqi;
        Vd[5] += ((v0*Al[1]-v1*Al[0])+(w0*Al[4]-w1*Al[3]))*dqi + Al[5]*ddqi;
      }
      float gv[6], gvd[6];
      gmatvec2_sym(&sGu[i*24], V, Vd, gv, gvd);
      {
        float w0=V[0],w1=V[1],w2=V[2],v0=V[3],v1=V[4],v2=V[5];
        float s0 = gvd[0] + (w1*gv[2]-w2*gv[1]) + (v1*gv[5]-v2*gv[4]);
        float s1 = gvd[1] + (w2*gv[0]-w0*gv[2]) + (v2*gv[3]-v0*gv[5]);
        float s2 = gvd[2] + (w0*gv[1]-w1*gv[0]) + (v0*gv[4]-v1*gv[3]);
        float s3 = gvd[3] + (w1*gv[5]-w2*gv[4]);
        float s4 = gvd[4] + (w2*gv[3]-w0*gv[5]);
        float s5 = gvd[5] + (w0*gv[4]-w1*gv[3]);
        sacc_lds[(i*6+0)*64+t] = s0;
        sacc_lds[(i*6+1)*64+t] = s1;
        sacc_lds[(i*6+2)*64+t] = s2;
        sacc_lds[(i*6+3)*64+t] = s3;
        sacc_lds[(i*6+4)*64+t] = s4;
        sacc_lds[(i*6+5)*64+t] = s5;
      }
    }
    __syncthreads();   // sacc ordering (cheap: 1 wave/block)

    // ---- backward sweep: ROLLED ----
    {
      float F[6];
      #pragma unroll
      for (int k=0;k<6;k++) F[k] = Fend[k];
      #pragma unroll 1
      for (int i=6;i>=0;i--){
        if (i<6){
          float Tl[12];
          #pragma unroll
          for (int k=0;k<12;k++) Tl[k] = W[(i+1)*12+k];
          adT_apply(Tl, Tl+9, F, F);
        }
        #pragma unroll
        for (int k=0;k<6;k++) F[k] += sacc_lds[(i*6+k)*64+t];
        float Al[6];
        #pragma unroll
        for (int k=0;k<6;k++) Al[k] = sA8[i*8+k];
        m_lds[i*64+t] = F[0]*Al[0]+F[1]*Al[1]+F[2]*Al[2]
                      + F[3]*Al[3]+F[4]*Al[4]+F[5]*Al[5];
      }
    }
    __syncthreads();   // m visible across the 8-lane group

    // ---- in-register solve (unrolled; gathers now direct LDS reads) ----
    float U[7][7];
    #pragma unroll
    for (int i=0;i<7;i++){
      #pragma unroll
      for (int j=i;j<7;j++) U[i][j] = m_lds[j*64 + e*8 + i];
    }
    float rv[7];
    #pragma unroll
    for (int i=0;i<7;i++) rv[i] = qf[i] - m_lds[i*64 + e*8 + 7];
    #pragma unroll
    for (int k=0;k<7;k++){
      float dinv = frcp(U[k][k]);          // SPD: no pivoting
      #pragma unroll
      for (int i=k+1;i<7;i++){
        float f = U[k][i]*dinv;
        #pragma unroll
        for (int j=i;j<7;j++) U[i][j] -= f*U[k][j];
        rv[i] -= f*rv[k];
      }
    }
    float x[7];
    #pragma unroll
    for (int i=6;i>=0;i--){
      float s = rv[i];
      #pragma unroll
      for (int j=i+1;j<7;j++) s -= U[i][j]*x[j];
      x[i] = s*frcp(U[i][i]);
    }

    // ---- RK4 bookkeeping (static indexing, registers) ----
    #pragma unroll
    for (int i=0;i<7;i++){
      kq[i]  = dqs[i];
      kdd[i] = x[i];
      accq[i]  += wgt*dqs[i];
      accdq[i] += wgt*x[i];
    }
    __syncthreads();   // protect W/sacc/m before next stage's writes
  }

  // ---- wrap/clip ----
  float q1r=0.f, dq1r=0.f;
  #pragma unroll
  for (int c=0;c<7;c++){
    float xx = q0[c] + accq[c] + PI_F;
    float mm = xx - floorf(xx * INV_TWO_PI_F) * TWO_PI_F;
    float qv = mm - PI_F;
    float dv = dq0[c] + accdq[c];
    dv = fminf(fmaxf(dv, -MAX_VEL), MAX_VEL);
    q1r  = (r==c) ? qv : q1r;
    dq1r = (r==c) ? dv : dq1r;
  }

  // ---- FK tree (unchanged from r6) ----
  {
    float XR[9], Xp[3];
    if (r < 7){
      float Re[9], Pe[3];
      exp_se3_Rp(&sA8[r*8], q1r, Re, Pe);
      mul33(&sMR[r*9], Re, XR);
      #pragma unroll
      for (int rr=0;rr<3;rr++)
        Xp[rr] = sMR[r*9+rr*3+0]*Pe[0]+sMR[r*9+rr*3+1]*Pe[1]+sMR[r*9+rr*3+2]*Pe[2] + sMp[r*3+rr];
    } else {
      #pragma unroll
      for (int k=0;k<9;k++) XR[k] = sMR[63+k];
      #pragma unroll
      for (int k=0;k<3;k++) Xp[k] = sMp[21+k];
    }
    #pragma unroll
    for (int k=0;k<9;k++) W[r*12+k]   = XR[k];
    #pragma unroll
    for (int k=0;k<3;k++) W[r*12+9+k] = Xp[k];
  }
  __syncthreads();

  #pragma unroll
  for (int w=4; w>=1; w>>=1){
    float Ra[9], pa[3], Rb[9], pb[3];
    if (r < w){
      #pragma unroll
      for (int k=0;k<9;k++){ Ra[k]=W[(2*r)*12+k]; Rb[k]=W[(2*r+1)*12+k]; }
      #pragma unroll
      for (int k=0;k<3;k++){ pa[k]=W[(2*r)*12+9+k]; pb[k]=W[(2*r+1)*12+9+k]; }
    }
    __syncthreads();
    if (r < w){
      float Rc[9];
      mul33(Ra, Rb, Rc);
      #pragma unroll
      for (int k=0;k<9;k++) W[r*12+k] = Rc[k];
      #pragma unroll
      for (int rr=0;rr<3;rr++)
        W[r*12+9+rr] = Ra[rr*3+0]*pb[0]+Ra[rr*3+1]*pb[1]+Ra[rr*3+2]*pb[2] + pa[rr];
    }
    __syncthreads();
  }

  // ---- stores ----
  if (r < 7){
    stv(g_out, b*14+r,   q1r,  isb);
    stv(g_out, b*14+7+r, dq1r, isb);
  } else {
    stv(g_out, B*14 + b*2 + 0, W[9],  isb);
    stv(g_out, B*14 + b*2 + 1, W[10], isb);
  }
}

extern "C" void kernel_launch(void* const* d_in, const int* in_sizes, int n_in,
                              void* d_out, int out_size, void* d_ws, size_t ws_size,
                              hipStream_t stream) {
  const int B = in_sizes[0] / 14;
  const int blocks = (B + 7) / 8;
  arm_rk4_kernel<<<blocks, 64, 0, stream>>>(d_in[0], d_in[1], d_in[2], d_in[3],
                                            d_in[4], d_in[5], d_in[6], d_out, B);
}

// Round 8
// 95.121 us; speedup vs baseline: 5.0681x; 1.0141x over previous
//
#include <hip/hip_runtime.h>
#include <hip/hip_bf16.h>

#define DTC 0.1f
#define ACTION_RANGE 50.0f
#define MAX_VEL 20.0f
#define PI_F 3.14159265358979323846f
#define TWO_PI_F 6.28318530717958647692f
#define INV_TWO_PI_F 0.15915494309189533577f

__device__ __forceinline__ float bf2f(__hip_bfloat16 x){ return __bfloat162float(x); }
__device__ __forceinline__ float frcp(float x){ return __builtin_amdgcn_rcpf(x); }

__device__ __forceinline__ float ldv(const void* p, int i, bool isb){
  return isb ? __bfloat162float(((const __hip_bfloat16*)p)[i]) : ((const float*)p)[i];
}
__device__ __forceinline__ void stv(void* p, int i, float v, bool isb){
  if (isb) ((__hip_bfloat16*)p)[i] = __float2bfloat16(v);
  else     ((float*)p)[i] = v;
}

// Branchless exp(se3): native __sinf/__cosf + Taylor blend (validated r1/2/4/6/7).
__device__ __forceinline__ void exp_se3_Rp(const float* Aj, float s, float* R, float* P){
  float wx=Aj[0]*s, wy=Aj[1]*s, wz=Aj[2]*s;
  float vx=Aj[3]*s, vy=Aj[4]*s, vz=Aj[5]*s;
  float th2 = wx*wx+wy*wy+wz*wz;
  float th = sqrtf(th2);
  float th4 = th2*th2;
  float aS = 1.f - th2*(1.f/6.f)  + th4*(1.f/120.f);
  float bS = 0.5f - th2*(1.f/24.f) + th4*(1.f/720.f);
  float cS = (1.f/6.f) - th2*(1.f/120.f) + th4*(1.f/5040.f);
  float sn = __sinf(th), cs = __cosf(th);
  float inv = frcp(th), inv2 = inv*inv;
  float aL = sn*inv;
  float bL = (1.f-cs)*inv2;
  float cL = (th-sn)*inv2*inv;
  bool sm = th < 0.25f;
  float a = sm?aS:aL, b = sm?bS:bL, c = sm?cS:cL;
  R[0]=1.f+b*(wx*wx-th2); R[1]=b*wx*wy-a*wz;      R[2]=b*wx*wz+a*wy;
  R[3]=b*wx*wy+a*wz;      R[4]=1.f+b*(wy*wy-th2); R[5]=b*wy*wz-a*wx;
  R[6]=b*wx*wz-a*wy;      R[7]=b*wy*wz+a*wx;      R[8]=1.f+b*(wz*wz-th2);
  float V0=1.f+c*(wx*wx-th2), V1=c*wx*wy-b*wz,      V2=c*wx*wz+b*wy;
  float V3=c*wx*wy+b*wz,      V4=1.f+c*(wy*wy-th2), V5=c*wy*wz-b*wx;
  float V6=c*wx*wz-b*wy,      V7=c*wy*wz+b*wx,      V8=1.f+c*(wz*wz-th2);
  P[0]=V0*vx+V1*vy+V2*vz;
  P[1]=V3*vx+V4*vy+V5*vz;
  P[2]=V6*vx+V7*vy+V8*vz;
}

__device__ __forceinline__ void mul33(const float* X, const float* Y, float* Z){
  #pragma unroll
  for (int r=0;r<3;r++){
    float x0=X[r*3+0], x1=X[r*3+1], x2=X[r*3+2];
    Z[r*3+0]=x0*Y[0]+x1*Y[3]+x2*Y[6];
    Z[r*3+1]=x0*Y[1]+x1*Y[4]+x2*Y[7];
    Z[r*3+2]=x0*Y[2]+x1*Y[5]+x2*Y[8];
  }
}

__device__ __forceinline__ void ad_apply(const float* R, const float* p, const float* Vin, float* Vout){
  float i0=Vin[0],i1=Vin[1],i2=Vin[2],i3=Vin[3],i4=Vin[4],i5=Vin[5];
  float w0 = R[0]*i0+R[1]*i1+R[2]*i2;
  float w1 = R[3]*i0+R[4]*i1+R[5]*i2;
  float w2 = R[6]*i0+R[7]*i1+R[8]*i2;
  float r0 = R[0]*i3+R[1]*i4+R[2]*i5;
  float r1 = R[3]*i3+R[4]*i4+R[5]*i5;
  float r2 = R[6]*i3+R[7]*i4+R[8]*i5;
  float p0=p[0],p1=p[1],p2=p[2];
  Vout[0]=w0; Vout[1]=w1; Vout[2]=w2;
  Vout[3]=p1*w2-p2*w1+r0;
  Vout[4]=p2*w0-p0*w2+r1;
  Vout[5]=p0*w1-p1*w0+r2;
}

__device__ __forceinline__ void adT_apply(const float* R, const float* p, const float* Fin, float* Fout){
  float m0=Fin[0],m1=Fin[1],m2=Fin[2],f0=Fin[3],f1=Fin[4],f2=Fin[5];
  float p0=p[0],p1=p[1],p2=p[2];
  float cx = m0 - (p1*f2 - p2*f1);
  float cy = m1 - (p2*f0 - p0*f2);
  float cz = m2 - (p0*f1 - p1*f0);
  float o0 = R[0]*cx + R[3]*cy + R[6]*cz;
  float o1 = R[1]*cx + R[4]*cy + R[7]*cz;
  float o2 = R[2]*cx + R[5]*cy + R[8]*cz;
  float o3 = R[0]*f0 + R[3]*f1 + R[6]*f2;
  float o4 = R[1]*f0 + R[4]*f1 + R[7]*f2;
  float o5 = R[2]*f0 + R[5]*f1 + R[8]*f2;
  Fout[0]=o0;Fout[1]=o1;Fout[2]=o2;Fout[3]=o3;Fout[4]=o4;Fout[5]=o5;
}

// Both G-matvecs from symmetric-packed Gu (validated r6/r7; identical FMA order).
__device__ __forceinline__ void gmatvec2_sym(const float* Gu, const float* v, const float* d,
                                             float* gv, float* gvd){
  float g0=Gu[0],g1=Gu[1],g2=Gu[2],g3=Gu[3],g4=Gu[4],g5=Gu[5];
  float g6=Gu[6],g7=Gu[7],g8=Gu[8],g9=Gu[9],g10=Gu[10];
  float g11=Gu[11],g12=Gu[12],g13=Gu[13],g14=Gu[14];
  float g15=Gu[15],g16=Gu[16],g17=Gu[17],g18=Gu[18],g19=Gu[19],g20=Gu[20];
  gv[0]=g0*v[0]+g1 *v[1]+g2 *v[2]+g3 *v[3]+g4 *v[4]+g5 *v[5];
  gv[1]=g1*v[0]+g6 *v[1]+g7 *v[2]+g8 *v[3]+g9 *v[4]+g10*v[5];
  gv[2]=g2*v[0]+g7 *v[1]+g11*v[2]+g12*v[3]+g13*v[4]+g14*v[5];
  gv[3]=g3*v[0]+g8 *v[1]+g12*v[2]+g15*v[3]+g16*v[4]+g17*v[5];
  gv[4]=g4*v[0]+g9 *v[1]+g13*v[2]+g16*v[3]+g18*v[4]+g19*v[5];
  gv[5]=g5*v[0]+g10*v[1]+g14*v[2]+g17*v[3]+g19*v[4]+g20*v[5];
  gvd[0]=g0*d[0]+g1 *d[1]+g2 *d[2]+g3 *d[3]+g4 *d[4]+g5 *d[5];
  gvd[1]=g1*d[0]+g6 *d[1]+g7 *d[2]+g8 *d[3]+g9 *d[4]+g10*d[5];
  gvd[2]=g2*d[0]+g7 *d[1]+g11*d[2]+g12*d[3]+g13*d[4]+g14*d[5];
  gvd[3]=g3*d[0]+g8 *d[1]+g12*d[2]+g15*d[3]+g16*d[4]+g17*d[5];
  gvd[4]=g4*d[0]+g9 *d[1]+g13*d[2]+g16*d[3]+g18*d[4]+g19*d[5];
  gvd[5]=g5*d[0]+g10*d[1]+g14*d[2]+g17*d[3]+g19*d[4]+g20*d[5];
}

#define W_STRIDE 100   // e*400B and r*48B both 16B-aligned -> b128 merges

__global__ __launch_bounds__(64) void arm_rk4_kernel(
    const void* __restrict__ g_state,
    const void* __restrict__ g_torque,
    const void* __restrict__ g_M,
    const void* __restrict__ g_A,
    const void* __restrict__ g_L,
    const void* __restrict__ g_grav,
    const void* __restrict__ g_ftip,
    void* __restrict__ g_out,
    int B)
{
  __shared__ __align__(16) float sA8[56];     // A[7][8] padded
  __shared__ __align__(16) float sGu[168];    // G sym-packed, stride 24
  __shared__ float sMinvR[72];
  __shared__ float sMinvp[24];
  __shared__ float sMR[72];
  __shared__ float sMp[24];
  __shared__ float sgrav[3];
  __shared__ float sftip[6];
  __shared__ __align__(16) float sW[8*W_STRIDE];
  // Rolled-loop indexed arrays (rule #20). sacc_lds/dqs_lds are THREAD-LOCAL
  // (written+read by the same lane) -> no barrier needed around them.
  __shared__ float sacc_lds[7*6*64];  // [joint][k][lane]
  __shared__ float m_lds[7*64];       // [joint][lane] (cross-lane: solve gathers)
  __shared__ float dqs_lds[7*8];      // [joint][element] (lane7-private)

  const bool isb = fabsf(bf2f(((const __hip_bfloat16*)g_grav)[1]) + 9.8f) < 0.5f;

  const int t = threadIdx.x;
  for (int x=t; x<56; x+=64){
    int i = x >> 3, k = x & 7;
    sA8[x] = (k < 6) ? ldv(g_A, i*6+k, isb) : 0.f;
  }
  for (int x=t; x<168; x+=64){
    int i = x/24; int u = x - i*24;
    if (u < 21){
      int rr = 0, u2 = u;
      while (u2 >= 6-rr){ u2 -= 6-rr; rr++; }   // init-only
      int cc = rr + u2;
      float s = 0.f;
      #pragma unroll
      for (int k=0;k<6;k++) s += ldv(g_L, i*36+rr*6+k, isb) * ldv(g_L, i*36+cc*6+k, isb);
      sGu[x] = s;
    } else sGu[x] = 0.f;
  }
  if (t < 8){
    float R[9], p[3];
    #pragma unroll
    for (int rr=0;rr<3;rr++){
      #pragma unroll
      for (int cc=0;cc<3;cc++) R[rr*3+cc] = ldv(g_M, t*16 + rr*4 + cc, isb);
      p[rr] = ldv(g_M, t*16 + rr*4 + 3, isb);
    }
    #pragma unroll
    for (int rr=0;rr<3;rr++){
      #pragma unroll
      for (int cc=0;cc<3;cc++){ sMR[t*9+rr*3+cc] = R[rr*3+cc]; sMinvR[t*9+rr*3+cc] = R[cc*3+rr]; }
      sMp[t*3+rr] = p[rr];
      sMinvp[t*3+rr] = -(R[0*3+rr]*p[0] + R[1*3+rr]*p[1] + R[2*3+rr]*p[2]);
    }
  }
  if (t == 0){ for (int k=0;k<3;k++) sgrav[k] = ldv(g_grav, k, isb); }
  if (t == 1){ for (int k=0;k<6;k++) sftip[k] = ldv(g_ftip, k, isb); }
  __syncthreads();

  const int e = t >> 3;
  const int r = t & 7;
  int b = blockIdx.x * 8 + e;
  if (b >= B) b = B - 1;
  const bool is7 = (r == 7);
  float* W = &sW[e*W_STRIDE];

  // ---- per-lane slim RK state (lane only ever consumes its OWN q/acc scalars;
  //      lane7's full-vector dq path goes through dqs_lds) ----
  float dq0[7], qf[7];
  #pragma unroll
  for (int i=0;i<7;i++){
    dq0[i] = ldv(g_state, b*14+7+i, isb);
    qf[i]  = ldv(g_torque, b*7+i, isb) * ACTION_RANGE;
  }
  float q0r = ldv(g_state, b*14 + (is7 ? 0 : r), isb);   // lane7: unused
  float dq0r = 0.f;
  #pragma unroll
  for (int c=0;c<7;c++) dq0r = (r==c) ? dq0[c] : dq0r;

  float px[7];                 // previous stage's qacc solution (k_dd)
  #pragma unroll
  for (int i=0;i<7;i++) px[i] = 0.f;
  float pxr = 0.f, pdqr = 0.f; // own-scalar carries
  float accq_r = 0.f, accdq_r = 0.f;

  float Fend[6];
  {
    float tf[6]; adT_apply(&sMinvR[63], &sMinvp[21], sftip, tf);
    #pragma unroll
    for (int k=0;k<6;k++) Fend[k] = is7 ? tf[k] : 0.f;
  }

  #pragma unroll 1
  for (int st=0; st<4; ++st){
    const float cin = (st==0) ? 0.f : ((st==3) ? DTC : 0.5f*DTC);
    const float wgt = (st==0||st==3) ? (DTC/6.f) : (DTC/3.f);
    const float dqsr = dq0r + cin*pxr;   // own dqs (bit-identical to old dqs[r])
    const float qsr  = q0r  + cin*pdqr;  // own qs

    // lane7 publishes its full dqs vector (thread-local LDS, read only by itself)
    if (is7){
      #pragma unroll
      for (int i=0;i<7;i++) dqs_lds[i*8+e] = dq0[i] + cin*px[i];
    }

    // ---- transforms (unrolled, per-lane) -> W ----
    if (r < 7){
      float Re[9], Pe[3], Rt[9];
      exp_se3_Rp(&sA8[r*8], -qsr, Re, Pe);
      mul33(Re, &sMinvR[r*9], Rt);
      float Tw[12];
      #pragma unroll
      for (int k=0;k<9;k++) Tw[k] = Rt[k];
      #pragma unroll
      for (int rr=0;rr<3;rr++)
        Tw[9+rr] = Re[rr*3+0]*sMinvp[r*3+0] + Re[rr*3+1]*sMinvp[r*3+1]
                 + Re[rr*3+2]*sMinvp[r*3+2] + Pe[rr];
      #pragma unroll
      for (int k=0;k<12;k++) W[r*12+k] = Tw[k];
    }
    __syncthreads();   // barrier A: W cross-lane (also fences prev-stage m_lds reads)

    // ---- forward sweep: rolled x2 (cross-iteration load pipelining) ----
    float V[6] = {0,0,0,0,0,0};
    float Vd[6];
    Vd[0]=0.f; Vd[1]=0.f; Vd[2]=0.f;
    Vd[3] = is7 ? -sgrav[0] : 0.f;
    Vd[4] = is7 ? -sgrav[1] : 0.f;
    Vd[5] = is7 ? -sgrav[2] : 0.f;
    #pragma unroll 2
    for (int i=0;i<7;i++){
      float Tl[12];
      #pragma unroll
      for (int k=0;k<12;k++) Tl[k] = W[i*12+k];
      float Al[6];
      #pragma unroll
      for (int k=0;k<6;k++) Al[k] = sA8[i*8+k];
      float dqi  = is7 ? dqs_lds[i*8+e] : 0.f;
      float ddqi = (!is7 && r==i) ? 1.f : 0.f;
      ad_apply(Tl, Tl+9, V, V);
      #pragma unroll
      for (int k=0;k<6;k++) V[k] += Al[k]*dqi;
      ad_apply(Tl, Tl+9, Vd, Vd);
      {
        float w0=V[0],w1=V[1],w2=V[2],v0=V[3],v1=V[4],v2=V[5];
        Vd[0] += (w1*Al[2]-w2*Al[1])*dqi + Al[0]*ddqi;
        Vd[1] += (w2*Al[0]-w0*Al[2])*dqi + Al[1]*ddqi;
        Vd[2] += (w0*Al[1]-w1*Al[0])*dqi + Al[2]*ddqi;
        Vd[3] += ((v1*Al[2]-v2*Al[1])+(w1*Al[5]-w2*Al[4]))*dqi + Al[3]*ddqi;
        Vd[4] += ((v2*Al[0]-v0*Al[2])+(w2*Al[3]-w0*Al[5]))*dqi + Al[4]*ddqi;
        Vd[5] += ((v0*Al[1]-v1*Al[0])+(w0*Al[4]-w1*Al[3]))*dqi + Al[5]*ddqi;
      }
      float gv[6], gvd[6];
      gmatvec2_sym(&sGu[i*24], V, Vd, gv, gvd);
      {
        float w0=V[0],w1=V[1],w2=V[2],v0=V[3],v1=V[4],v2=V[5];
        sacc_lds[(i*6+0)*64+t] = gvd[0] + (w1*gv[2]-w2*gv[1]) + (v1*gv[5]-v2*gv[4]);
        sacc_lds[(i*6+1)*64+t] = gvd[1] + (w2*gv[0]-w0*gv[2]) + (v2*gv[3]-v0*gv[5]);
        sacc_lds[(i*6+2)*64+t] = gvd[2] + (w0*gv[1]-w1*gv[0]) + (v0*gv[4]-v1*gv[3]);
        sacc_lds[(i*6+3)*64+t] = gvd[3] + (w1*gv[5]-w2*gv[4]);
        sacc_lds[(i*6+4)*64+t] = gvd[4] + (w2*gv[3]-w0*gv[5]);
        sacc_lds[(i*6+5)*64+t] = gvd[5] + (w0*gv[4]-w1*gv[3]);
      }
    }
    // NO barrier here: sacc_lds is thread-local; W unchanged since barrier A.

    // ---- backward sweep: rolled x2 ----
    {
      float F[6];
      #pragma unroll
      for (int k=0;k<6;k++) F[k] = Fend[k];
      #pragma unroll 2
      for (int i=6;i>=0;i--){
        if (i<6){
          float Tl[12];
          #pragma unroll
          for (int k=0;k<12;k++) Tl[k] = W[(i+1)*12+k];
          adT_apply(Tl, Tl+9, F, F);
        }
        #pragma unroll
        for (int k=0;k<6;k++) F[k] += sacc_lds[(i*6+k)*64+t];
        float Al[6];
        #pragma unroll
        for (int k=0;k<6;k++) Al[k] = sA8[i*8+k];
        m_lds[i*64+t] = F[0]*Al[0]+F[1]*Al[1]+F[2]*Al[2]
                      + F[3]*Al[3]+F[4]*Al[4]+F[5]*Al[5];
      }
    }
    __syncthreads();   // barrier B: m_lds cross-lane before solve gathers

    // ---- in-register solve (unrolled; gathers are direct LDS reads) ----
    float U[7][7];
    #pragma unroll
    for (int i=0;i<7;i++){
      #pragma unroll
      for (int j=i;j<7;j++) U[i][j] = m_lds[j*64 + e*8 + i];
    }
    float rv[7];
    #pragma unroll
    for (int i=0;i<7;i++) rv[i] = qf[i] - m_lds[i*64 + e*8 + 7];
    #pragma unroll
    for (int k=0;k<7;k++){
      float dinv = frcp(U[k][k]);          // SPD: no pivoting
      #pragma unroll
      for (int i=k+1;i<7;i++){
        float f = U[k][i]*dinv;
        #pragma unroll
        for (int j=i;j<7;j++) U[i][j] -= f*U[k][j];
        rv[i] -= f*rv[k];
      }
    }
    float x[7];
    #pragma unroll
    for (int i=6;i>=0;i--){
      float s = rv[i];
      #pragma unroll
      for (int j=i+1;j<7;j++) s -= U[i][j]*x[j];
      x[i] = s*frcp(U[i][i]);
    }

    // ---- slim RK bookkeeping (own scalars + px vector for lane7's path) ----
    float xr = 0.f;
    #pragma unroll
    for (int c=0;c<7;c++) xr = (r==c) ? x[c] : xr;
    accq_r  += wgt*dqsr;
    accdq_r += wgt*xr;
    pdqr = dqsr;
    pxr  = xr;
    #pragma unroll
    for (int i=0;i<7;i++) px[i] = x[i];
    // NO end-of-stage barrier: next stage's barrier A separates this stage's
    // m_lds solve-reads from the next backward's m_lds writes, and this
    // stage's last W read (backward) from the next transforms' W writes.
  }

  // ---- wrap/clip (own scalars) ----
  float q1r, dq1r;
  {
    float xx = q0r + accq_r + PI_F;
    float mm = xx - floorf(xx * INV_TWO_PI_F) * TWO_PI_F;
    q1r = mm - PI_F;
    float dv = dq0r + accdq_r;
    dq1r = fminf(fmaxf(dv, -MAX_VEL), MAX_VEL);
  }

  // ---- FK tree (unchanged) ----
  {
    float XR[9], Xp[3];
    if (r < 7){
      float Re[9], Pe[3];
      exp_se3_Rp(&sA8[r*8], q1r, Re, Pe);
      mul33(&sMR[r*9], Re, XR);
      #pragma unroll
      for (int rr=0;rr<3;rr++)
        Xp[rr] = sMR[r*9+rr*3+0]*Pe[0]+sMR[r*9+rr*3+1]*Pe[1]+sMR[r*9+rr*3+2]*Pe[2] + sMp[r*3+rr];
    } else {
      #pragma unroll
      for (int k=0;k<9;k++) XR[k] = sMR[63+k];
      #pragma unroll
      for (int k=0;k<3;k++) Xp[k] = sMp[21+k];
    }
    #pragma unroll
    for (int k=0;k<9;k++) W[r*12+k]   = XR[k];
    #pragma unroll
    for (int k=0;k<3;k++) W[r*12+9+k] = Xp[k];
  }
  __syncthreads();

  #pragma unroll
  for (int w=4; w>=1; w>>=1){
    float Ra[9], pa[3], Rb[9], pb[3];
    if (r < w){
      #pragma unroll
      for (int k=0;k<9;k++){ Ra[k]=W[(2*r)*12+k]; Rb[k]=W[(2*r+1)*12+k]; }
      #pragma unroll
      for (int k=0;k<3;k++){ pa[k]=W[(2*r)*12+9+k]; pb[k]=W[(2*r+1)*12+9+k]; }
    }
    __syncthreads();
    if (r < w){
      float Rc[9];
      mul33(Ra, Rb, Rc);
      #pragma unroll
      for (int k=0;k<9;k++) W[r*12+k] = Rc[k];
      #pragma unroll
      for (int rr=0;rr<3;rr++)
        W[r*12+9+rr] = Ra[rr*3+0]*pb[0]+Ra[rr*3+1]*pb[1]+Ra[rr*3+2]*pb[2] + pa[rr];
    }
    __syncthreads();
  }

  // ---- stores ----
  if (r < 7){
    stv(g_out, b*14+r,   q1r,  isb);
    stv(g_out, b*14+7+r, dq1r, isb);
  } else {
    stv(g_out, B*14 + b*2 + 0, W[9],  isb);
    stv(g_out, B*14 + b*2 + 1, W[10], isb);
  }
}

extern "C" void kernel_launch(void* const* d_in, const int* in_sizes, int n_in,
                              void* d_out, int out_size, void* d_ws, size_t ws_size,
                              hipStream_t stream) {
  const int B = in_sizes[0] / 14;
  const int blocks = (B + 7) / 8;
  arm_rk4_kernel<<<blocks, 64, 0, stream>>>(d_in[0], d_in[1], d_in[2], d_in[3],
                                            d_in[4], d_in[5], d_in[6], d_out, B);
}

// Round 9
// 94.853 us; speedup vs baseline: 5.0824x; 1.0028x over previous
//
#include <hip/hip_runtime.h>
#include <hip/hip_bf16.h>

#define DTC 0.1f
#define ACTION_RANGE 50.0f
#define MAX_VEL 20.0f
#define PI_F 3.14159265358979323846f
#define TWO_PI_F 6.28318530717958647692f
#define INV_TWO_PI_F 0.15915494309189533577f

__device__ __forceinline__ float bf2f(__hip_bfloat16 x){ return __bfloat162float(x); }
__device__ __forceinline__ float frcp(float x){ return __builtin_amdgcn_rcpf(x); }

__device__ __forceinline__ float ldv(const void* p, int i, bool isb){
  return isb ? __bfloat162float(((const __hip_bfloat16*)p)[i]) : ((const float*)p)[i];
}
__device__ __forceinline__ void stv(void* p, int i, float v, bool isb){
  if (isb) ((__hip_bfloat16*)p)[i] = __float2bfloat16(v);
  else     ((float*)p)[i] = v;
}

// Branchless exp(se3): native __sinf/__cosf + Taylor blend (validated r1-r8).
// At s==0: small path -> R=I, P=0 exactly (used by the uniform lane-7 FK path).
__device__ __forceinline__ void exp_se3_Rp(const float* Aj, float s, float* R, float* P){
  float wx=Aj[0]*s, wy=Aj[1]*s, wz=Aj[2]*s;
  float vx=Aj[3]*s, vy=Aj[4]*s, vz=Aj[5]*s;
  float th2 = wx*wx+wy*wy+wz*wz;
  float th = sqrtf(th2);
  float th4 = th2*th2;
  float aS = 1.f - th2*(1.f/6.f)  + th4*(1.f/120.f);
  float bS = 0.5f - th2*(1.f/24.f) + th4*(1.f/720.f);
  float cS = (1.f/6.f) - th2*(1.f/120.f) + th4*(1.f/5040.f);
  float sn = __sinf(th), cs = __cosf(th);
  float inv = frcp(th), inv2 = inv*inv;
  float aL = sn*inv;
  float bL = (1.f-cs)*inv2;
  float cL = (th-sn)*inv2*inv;
  bool sm = th < 0.25f;
  float a = sm?aS:aL, b = sm?bS:bL, c = sm?cS:cL;
  R[0]=1.f+b*(wx*wx-th2); R[1]=b*wx*wy-a*wz;      R[2]=b*wx*wz+a*wy;
  R[3]=b*wx*wy+a*wz;      R[4]=1.f+b*(wy*wy-th2); R[5]=b*wy*wz-a*wx;
  R[6]=b*wx*wz-a*wy;      R[7]=b*wy*wz+a*wx;      R[8]=1.f+b*(wz*wz-th2);
  float V0=1.f+c*(wx*wx-th2), V1=c*wx*wy-b*wz,      V2=c*wx*wz+b*wy;
  float V3=c*wx*wy+b*wz,      V4=1.f+c*(wy*wy-th2), V5=c*wy*wz-b*wx;
  float V6=c*wx*wz-b*wy,      V7=c*wy*wz+b*wx,      V8=1.f+c*(wz*wz-th2);
  P[0]=V0*vx+V1*vy+V2*vz;
  P[1]=V3*vx+V4*vy+V5*vz;
  P[2]=V6*vx+V7*vy+V8*vz;
}

__device__ __forceinline__ void mul33(const float* X, const float* Y, float* Z){
  #pragma unroll
  for (int r=0;r<3;r++){
    float x0=X[r*3+0], x1=X[r*3+1], x2=X[r*3+2];
    Z[r*3+0]=x0*Y[0]+x1*Y[3]+x2*Y[6];
    Z[r*3+1]=x0*Y[1]+x1*Y[4]+x2*Y[7];
    Z[r*3+2]=x0*Y[2]+x1*Y[5]+x2*Y[8];
  }
}

__device__ __forceinline__ void ad_apply(const float* R, const float* p, const float* Vin, float* Vout){
  float i0=Vin[0],i1=Vin[1],i2=Vin[2],i3=Vin[3],i4=Vin[4],i5=Vin[5];
  float w0 = R[0]*i0+R[1]*i1+R[2]*i2;
  float w1 = R[3]*i0+R[4]*i1+R[5]*i2;
  float w2 = R[6]*i0+R[7]*i1+R[8]*i2;
  float r0 = R[0]*i3+R[1]*i4+R[2]*i5;
  float r1 = R[3]*i3+R[4]*i4+R[5]*i5;
  float r2 = R[6]*i3+R[7]*i4+R[8]*i5;
  float p0=p[0],p1=p[1],p2=p[2];
  Vout[0]=w0; Vout[1]=w1; Vout[2]=w2;
  Vout[3]=p1*w2-p2*w1+r0;
  Vout[4]=p2*w0-p0*w2+r1;
  Vout[5]=p0*w1-p1*w0+r2;
}

__device__ __forceinline__ void adT_apply(const float* R, const float* p, const float* Fin, float* Fout){
  float m0=Fin[0],m1=Fin[1],m2=Fin[2],f0=Fin[3],f1=Fin[4],f2=Fin[5];
  float p0=p[0],p1=p[1],p2=p[2];
  float cx = m0 - (p1*f2 - p2*f1);
  float cy = m1 - (p2*f0 - p0*f2);
  float cz = m2 - (p0*f1 - p1*f0);
  float o0 = R[0]*cx + R[3]*cy + R[6]*cz;
  float o1 = R[1]*cx + R[4]*cy + R[7]*cz;
  float o2 = R[2]*cx + R[5]*cy + R[8]*cz;
  float o3 = R[0]*f0 + R[3]*f1 + R[6]*f2;
  float o4 = R[1]*f0 + R[4]*f1 + R[7]*f2;
  float o5 = R[2]*f0 + R[5]*f1 + R[8]*f2;
  Fout[0]=o0;Fout[1]=o1;Fout[2]=o2;Fout[3]=o3;Fout[4]=o4;Fout[5]=o5;
}

// Both G-matvecs from symmetric-packed Gu (validated r6/r7/r8; identical FMA order).
__device__ __forceinline__ void gmatvec2_sym(const float* Gu, const float* v, const float* d,
                                             float* gv, float* gvd){
  float g0=Gu[0],g1=Gu[1],g2=Gu[2],g3=Gu[3],g4=Gu[4],g5=Gu[5];
  float g6=Gu[6],g7=Gu[7],g8=Gu[8],g9=Gu[9],g10=Gu[10];
  float g11=Gu[11],g12=Gu[12],g13=Gu[13],g14=Gu[14];
  float g15=Gu[15],g16=Gu[16],g17=Gu[17],g18=Gu[18],g19=Gu[19],g20=Gu[20];
  gv[0]=g0*v[0]+g1 *v[1]+g2 *v[2]+g3 *v[3]+g4 *v[4]+g5 *v[5];
  gv[1]=g1*v[0]+g6 *v[1]+g7 *v[2]+g8 *v[3]+g9 *v[4]+g10*v[5];
  gv[2]=g2*v[0]+g7 *v[1]+g11*v[2]+g12*v[3]+g13*v[4]+g14*v[5];
  gv[3]=g3*v[0]+g8 *v[1]+g12*v[2]+g15*v[3]+g16*v[4]+g17*v[5];
  gv[4]=g4*v[0]+g9 *v[1]+g13*v[2]+g16*v[3]+g18*v[4]+g19*v[5];
  gv[5]=g5*v[0]+g10*v[1]+g14*v[2]+g17*v[3]+g19*v[4]+g20*v[5];
  gvd[0]=g0*d[0]+g1 *d[1]+g2 *d[2]+g3 *d[3]+g4 *d[4]+g5 *d[5];
  gvd[1]=g1*d[0]+g6 *d[1]+g7 *d[2]+g8 *d[3]+g9 *d[4]+g10*d[5];
  gvd[2]=g2*d[0]+g7 *d[1]+g11*d[2]+g12*d[3]+g13*d[4]+g14*d[5];
  gvd[3]=g3*d[0]+g8 *d[1]+g12*d[2]+g15*d[3]+g16*d[4]+g17*d[5];
  gvd[4]=g4*d[0]+g9 *d[1]+g13*d[2]+g16*d[3]+g18*d[4]+g19*d[5];
  gvd[5]=g5*d[0]+g10*d[1]+g14*d[2]+g17*d[3]+g19*d[4]+g20*d[5];
}

#define W_STRIDE 100   // e*400B and r*48B both 16B-aligned -> b128 merges

__global__ __launch_bounds__(64) void arm_rk4_kernel(
    const void* __restrict__ g_state,
    const void* __restrict__ g_torque,
    const void* __restrict__ g_M,
    const void* __restrict__ g_A,
    const void* __restrict__ g_L,
    const void* __restrict__ g_grav,
    const void* __restrict__ g_ftip,
    void* __restrict__ g_out,
    int B)
{
  __shared__ __align__(16) float sA8[56];     // A[7][8] padded
  __shared__ __align__(16) float sGu[168];    // G sym-packed, stride 24
  __shared__ float sMinvR[72];
  __shared__ float sMinvp[24];
  __shared__ float sMR[72];
  __shared__ float sMp[24];
  __shared__ float sgrav[3];
  __shared__ float sftip[6];
  __shared__ __align__(16) float sW[8*W_STRIDE];
  // Rolled-loop indexed arrays (rule #20). sacc_lds/dqs_lds are THREAD-LOCAL
  // (written+read by the same lane) -> no barrier needed around them.
  __shared__ float sacc_lds[7*6*64];  // [joint][k][lane]
  __shared__ float m_lds[7*64];       // [joint][lane] (cross-lane: solve gathers)
  __shared__ float dqs_lds[7*8];      // [joint][element] (lane7-private)

  const bool isb = fabsf(bf2f(((const __hip_bfloat16*)g_grav)[1]) + 9.8f) < 0.5f;

  const int t = threadIdx.x;
  for (int x=t; x<56; x+=64){
    int i = x >> 3, k = x & 7;
    sA8[x] = (k < 6) ? ldv(g_A, i*6+k, isb) : 0.f;
  }
  for (int x=t; x<168; x+=64){
    int i = x/24; int u = x - i*24;
    if (u < 21){
      int rr = 0, u2 = u;
      while (u2 >= 6-rr){ u2 -= 6-rr; rr++; }   // init-only
      int cc = rr + u2;
      float s = 0.f;
      #pragma unroll
      for (int k=0;k<6;k++) s += ldv(g_L, i*36+rr*6+k, isb) * ldv(g_L, i*36+cc*6+k, isb);
      sGu[x] = s;
    } else sGu[x] = 0.f;
  }
  if (t < 8){
    float R[9], p[3];
    #pragma unroll
    for (int rr=0;rr<3;rr++){
      #pragma unroll
      for (int cc=0;cc<3;cc++) R[rr*3+cc] = ldv(g_M, t*16 + rr*4 + cc, isb);
      p[rr] = ldv(g_M, t*16 + rr*4 + 3, isb);
    }
    #pragma unroll
    for (int rr=0;rr<3;rr++){
      #pragma unroll
      for (int cc=0;cc<3;cc++){ sMR[t*9+rr*3+cc] = R[rr*3+cc]; sMinvR[t*9+rr*3+cc] = R[cc*3+rr]; }
      sMp[t*3+rr] = p[rr];
      sMinvp[t*3+rr] = -(R[0*3+rr]*p[0] + R[1*3+rr]*p[1] + R[2*3+rr]*p[2]);
    }
  }
  if (t == 0){ for (int k=0;k<3;k++) sgrav[k] = ldv(g_grav, k, isb); }
  if (t == 1){ for (int k=0;k<6;k++) sftip[k] = ldv(g_ftip, k, isb); }
  __syncthreads();

  const int e = t >> 3;
  const int r = t & 7;
  int b = blockIdx.x * 8 + e;
  if (b >= B) b = B - 1;
  const bool is7 = (r == 7);
  float* W = &sW[e*W_STRIDE];

  // ---- per-lane slim RK state (validated r8) ----
  float dq0[7], qf[7];
  #pragma unroll
  for (int i=0;i<7;i++){
    dq0[i] = ldv(g_state, b*14+7+i, isb);
    qf[i]  = ldv(g_torque, b*7+i, isb) * ACTION_RANGE;
  }
  float q0r = ldv(g_state, b*14 + (is7 ? 0 : r), isb);   // lane7: unused
  float dq0r = 0.f;
  #pragma unroll
  for (int c=0;c<7;c++) dq0r = (r==c) ? dq0[c] : dq0r;

  float px[7];
  #pragma unroll
  for (int i=0;i<7;i++) px[i] = 0.f;
  float pxr = 0.f, pdqr = 0.f;
  float accq_r = 0.f, accdq_r = 0.f;

  float Fend[6];
  {
    float tf[6]; adT_apply(&sMinvR[63], &sMinvp[21], sftip, tf);
    #pragma unroll
    for (int k=0;k<6;k++) Fend[k] = is7 ? tf[k] : 0.f;
  }

  #pragma unroll 1
  for (int st=0; st<4; ++st){
    const float cin = (st==0) ? 0.f : ((st==3) ? DTC : 0.5f*DTC);
    const float wgt = (st==0||st==3) ? (DTC/6.f) : (DTC/3.f);
    const float dqsr = dq0r + cin*pxr;
    const float qsr  = q0r  + cin*pdqr;

    if (is7){
      #pragma unroll
      for (int i=0;i<7;i++) dqs_lds[i*8+e] = dq0[i] + cin*px[i];
    }

    // ---- transforms (unrolled, per-lane) -> W ----
    if (r < 7){
      float Re[9], Pe[3], Rt[9];
      exp_se3_Rp(&sA8[r*8], -qsr, Re, Pe);
      mul33(Re, &sMinvR[r*9], Rt);
      float Tw[12];
      #pragma unroll
      for (int k=0;k<9;k++) Tw[k] = Rt[k];
      #pragma unroll
      for (int rr=0;rr<3;rr++)
        Tw[9+rr] = Re[rr*3+0]*sMinvp[r*3+0] + Re[rr*3+1]*sMinvp[r*3+1]
                 + Re[rr*3+2]*sMinvp[r*3+2] + Pe[rr];
      #pragma unroll
      for (int k=0;k<12;k++) W[r*12+k] = Tw[k];
    }
    __syncthreads();   // barrier A: W cross-lane (also fences prev-stage m_lds reads)

    // ---- forward sweep: rolled x2 ----
    float V[6] = {0,0,0,0,0,0};
    float Vd[6];
    Vd[0]=0.f; Vd[1]=0.f; Vd[2]=0.f;
    Vd[3] = is7 ? -sgrav[0] : 0.f;
    Vd[4] = is7 ? -sgrav[1] : 0.f;
    Vd[5] = is7 ? -sgrav[2] : 0.f;
    #pragma unroll 2
    for (int i=0;i<7;i++){
      float Tl[12];
      #pragma unroll
      for (int k=0;k<12;k++) Tl[k] = W[i*12+k];
      float Al[6];
      #pragma unroll
      for (int k=0;k<6;k++) Al[k] = sA8[i*8+k];
      float dqi  = is7 ? dqs_lds[i*8+e] : 0.f;
      float ddqi = (!is7 && r==i) ? 1.f : 0.f;
      ad_apply(Tl, Tl+9, V, V);
      #pragma unroll
      for (int k=0;k<6;k++) V[k] += Al[k]*dqi;
      ad_apply(Tl, Tl+9, Vd, Vd);
      {
        float w0=V[0],w1=V[1],w2=V[2],v0=V[3],v1=V[4],v2=V[5];
        Vd[0] += (w1*Al[2]-w2*Al[1])*dqi + Al[0]*ddqi;
        Vd[1] += (w2*Al[0]-w0*Al[2])*dqi + Al[1]*ddqi;
        Vd[2] += (w0*Al[1]-w1*Al[0])*dqi + Al[2]*ddqi;
        Vd[3] += ((v1*Al[2]-v2*Al[1])+(w1*Al[5]-w2*Al[4]))*dqi + Al[3]*ddqi;
        Vd[4] += ((v2*Al[0]-v0*Al[2])+(w2*Al[3]-w0*Al[5]))*dqi + Al[4]*ddqi;
        Vd[5] += ((v0*Al[1]-v1*Al[0])+(w0*Al[4]-w1*Al[3]))*dqi + Al[5]*ddqi;
      }
      float gv[6], gvd[6];
      gmatvec2_sym(&sGu[i*24], V, Vd, gv, gvd);
      {
        float w0=V[0],w1=V[1],w2=V[2],v0=V[3],v1=V[4],v2=V[5];
        sacc_lds[(i*6+0)*64+t] = gvd[0] + (w1*gv[2]-w2*gv[1]) + (v1*gv[5]-v2*gv[4]);
        sacc_lds[(i*6+1)*64+t] = gvd[1] + (w2*gv[0]-w0*gv[2]) + (v2*gv[3]-v0*gv[5]);
        sacc_lds[(i*6+2)*64+t] = gvd[2] + (w0*gv[1]-w1*gv[0]) + (v0*gv[4]-v1*gv[3]);
        sacc_lds[(i*6+3)*64+t] = gvd[3] + (w1*gv[5]-w2*gv[4]);
        sacc_lds[(i*6+4)*64+t] = gvd[4] + (w2*gv[3]-w0*gv[5]);
        sacc_lds[(i*6+5)*64+t] = gvd[5] + (w0*gv[4]-w1*gv[3]);
      }
    }
    // NO barrier: sacc_lds thread-local; W unchanged since barrier A.

    // ---- backward sweep: rolled x2 ----
    {
      float F[6];
      #pragma unroll
      for (int k=0;k<6;k++) F[k] = Fend[k];
      #pragma unroll 2
      for (int i=6;i>=0;i--){
        if (i<6){
          float Tl[12];
          #pragma unroll
          for (int k=0;k<12;k++) Tl[k] = W[(i+1)*12+k];
          adT_apply(Tl, Tl+9, F, F);
        }
        #pragma unroll
        for (int k=0;k<6;k++) F[k] += sacc_lds[(i*6+k)*64+t];
        float Al[6];
        #pragma unroll
        for (int k=0;k<6;k++) Al[k] = sA8[i*8+k];
        m_lds[i*64+t] = F[0]*Al[0]+F[1]*Al[1]+F[2]*Al[2]
                      + F[3]*Al[3]+F[4]*Al[4]+F[5]*Al[5];
      }
    }
    __syncthreads();   // barrier B: m_lds cross-lane before solve gathers

    // ---- in-register solve (validated r4/r7/r8) ----
    float U[7][7];
    #pragma unroll
    for (int i=0;i<7;i++){
      #pragma unroll
      for (int j=i;j<7;j++) U[i][j] = m_lds[j*64 + e*8 + i];
    }
    float rv[7];
    #pragma unroll
    for (int i=0;i<7;i++) rv[i] = qf[i] - m_lds[i*64 + e*8 + 7];
    #pragma unroll
    for (int k=0;k<7;k++){
      float dinv = frcp(U[k][k]);          // SPD: no pivoting
      #pragma unroll
      for (int i=k+1;i<7;i++){
        float f = U[k][i]*dinv;
        #pragma unroll
        for (int j=i;j<7;j++) U[i][j] -= f*U[k][j];
        rv[i] -= f*rv[k];
      }
    }
    float x[7];
    #pragma unroll
    for (int i=6;i>=0;i--){
      float s = rv[i];
      #pragma unroll
      for (int j=i+1;j<7;j++) s -= U[i][j]*x[j];
      x[i] = s*frcp(U[i][i]);
    }

    // ---- slim RK bookkeeping ----
    float xr = 0.f;
    #pragma unroll
    for (int c=0;c<7;c++) xr = (r==c) ? x[c] : xr;
    accq_r  += wgt*dqsr;
    accdq_r += wgt*xr;
    pdqr = dqsr;
    pxr  = xr;
    #pragma unroll
    for (int i=0;i<7;i++) px[i] = x[i];
    // NO end-of-stage barrier (r8-validated: next barrier A covers the hazards).
  }

  // ---- wrap/clip (own scalars) ----
  float q1r, dq1r;
  {
    float xx = q0r + accq_r + PI_F;
    float mm = xx - floorf(xx * INV_TWO_PI_F) * TWO_PI_F;
    q1r = mm - PI_F;
    float dv = dq0r + accdq_r;
    dq1r = fminf(fmaxf(dv, -MAX_VEL), MAX_VEL);
  }

  // ---- FK: uniform X_r = M_r exp(A_r qfk) (lane7 qfk=0 -> X_7 = M_7 exactly),
  //      then Hillis-Steele 8-lane shuffle scan (r5-validated algebra; tail-only
  //      register pressure; zero barriers, zero LDS) ----
  float PR[9], Pp[3];
  {
    const int ar = is7 ? 6 : r;           // A row irrelevant at s=0
    const float qfk = is7 ? 0.f : q1r;
    float Re[9], Pe[3];
    exp_se3_Rp(&sA8[ar*8], qfk, Re, Pe);  // lane7: Re=I, Pe=0 exactly
    mul33(&sMR[r*9], Re, PR);
    #pragma unroll
    for (int rr=0;rr<3;rr++)
      Pp[rr] = sMR[r*9+rr*3+0]*Pe[0]+sMR[r*9+rr*3+1]*Pe[1]+sMR[r*9+rr*3+2]*Pe[2] + sMp[r*3+rr];
  }
  #pragma unroll
  for (int d=1; d<8; d<<=1){
    int src = (r>=d) ? (r-d) : 0;
    float Ra[9], pa[3];
    #pragma unroll
    for (int k=0;k<9;k++) Ra[k] = __shfl(PR[k], src, 8);
    #pragma unroll
    for (int k=0;k<3;k++) pa[k] = __shfl(Pp[k], src, 8);
    float Rn[9], pn[3];
    mul33(Ra, PR, Rn);
    #pragma unroll
    for (int rr=0;rr<3;rr++)
      pn[rr] = Ra[rr*3+0]*Pp[0]+Ra[rr*3+1]*Pp[1]+Ra[rr*3+2]*Pp[2] + pa[rr];
    bool use = (r>=d);
    #pragma unroll
    for (int k=0;k<9;k++) PR[k] = use ? Rn[k] : PR[k];
    #pragma unroll
    for (int k=0;k<3;k++) Pp[k] = use ? pn[k] : Pp[k];
  }

  // ---- stores ----
  if (r < 7){
    stv(g_out, b*14+r,   q1r,  isb);
    stv(g_out, b*14+7+r, dq1r, isb);
  } else {
    stv(g_out, B*14 + b*2 + 0, Pp[0], isb);
    stv(g_out, B*14 + b*2 + 1, Pp[1], isb);
  }
}

extern "C" void kernel_launch(void* const* d_in, const int* in_sizes, int n_in,
                              void* d_out, int out_size, void* d_ws, size_t ws_size,
                              hipStream_t stream) {
  const int B = in_sizes[0] / 14;
  const int blocks = (B + 7) / 8;
  arm_rk4_kernel<<<blocks, 64, 0, stream>>>(d_in[0], d_in[1], d_in[2], d_in[3],
                                            d_in[4], d_in[5], d_in[6], d_out, B);
}